// Round 1
// baseline (2655.211 us; speedup 1.0000x reference)
//
#include <hip/hip_runtime.h>

#define NB 8
#define SL 512
#define DM 1024
#define NH 16
#define DH 64
#define TK 32

// ---------------------------------------------------------------------------
// Generic tiled SGEMM: out[m,n] = ACT( sum_k A[m,k]*W[k,n] + bias[n] )
// A may be a k-concat of up to 3 sources (each row-stride DM).
// OUTMODE 0: row-major [4096,1024]; OUTMODE 1: [b,h,l,d] scatter (per-head).
// ACT: 0 none, 1 sigmoid, 2 relu.
// ---------------------------------------------------------------------------
template<int ACT, int OUTMODE>
__global__ __launch_bounds__(256)
void gemm_k(const float* __restrict__ A0, const float* __restrict__ A1,
            const float* __restrict__ A2,
            const int K1, const int K2, const int Ktot,
            const float* __restrict__ W, const float* __restrict__ bias,
            float* __restrict__ out)
{
    __shared__ float As[16][68];   // [k][m], padded
    __shared__ float Bs[16][68];   // [k][n], padded
    const int tid = threadIdx.x;
    const int ty = tid >> 4, tx = tid & 15;
    const int m0 = blockIdx.y * 64;
    const int n0 = blockIdx.x * 64;
    const int mA = tid >> 2;            // 0..63
    const int kA = (tid & 3) * 4;       // 0,4,8,12
    const int kB = tid >> 4;            // 0..15
    const int nB = (tid & 15) * 4;      // 0..60

    float acc[4][4] = {};
    for (int k0 = 0; k0 < Ktot; k0 += 16) {
        const int kk = k0 + kA;
        const float* src; int ko;
        if (kk < K1)      { src = A0; ko = kk; }
        else if (kk < K2) { src = A1; ko = kk - K1; }
        else              { src = A2; ko = kk - K2; }
        const float4 av = *(const float4*)(src + (size_t)(m0 + mA) * DM + ko);
        const float4 bv = *(const float4*)(W + (size_t)(k0 + kB) * DM + n0 + nB);
        __syncthreads();
        As[kA+0][mA] = av.x; As[kA+1][mA] = av.y;
        As[kA+2][mA] = av.z; As[kA+3][mA] = av.w;
        *(float4*)&Bs[kB][nB] = bv;
        __syncthreads();
        #pragma unroll
        for (int k = 0; k < 16; ++k) {
            const float4 a  = *(const float4*)&As[k][4*ty];
            const float4 b4 = *(const float4*)&Bs[k][4*tx];
            const float aa[4] = {a.x, a.y, a.z, a.w};
            const float bb[4] = {b4.x, b4.y, b4.z, b4.w};
            #pragma unroll
            for (int i = 0; i < 4; ++i)
                #pragma unroll
                for (int j = 0; j < 4; ++j)
                    acc[i][j] += aa[i] * bb[j];
        }
    }

    const int nb = n0 + 4*tx;
    const float4 bi = *(const float4*)(bias + nb);
    const float bias4[4] = {bi.x, bi.y, bi.z, bi.w};
    #pragma unroll
    for (int i = 0; i < 4; ++i) {
        const int m = m0 + 4*ty + i;
        float r[4];
        #pragma unroll
        for (int j = 0; j < 4; ++j) {
            float v = acc[i][j] + bias4[j];
            if (ACT == 1)      v = 1.f / (1.f + __expf(-v));
            else if (ACT == 2) v = v > 0.f ? v : 0.f;
            r[j] = v;
        }
        const float4 rv = {r[0], r[1], r[2], r[3]};
        if (OUTMODE == 0) {
            *(float4*)(out + (size_t)m * DM + nb) = rv;
        } else {
            const int bb_ = m >> 9, l = m & 511;
            const int hh  = nb >> 6, dd = nb & 63;
            *(float4*)(out + ((size_t)(bb_*NH + hh)*SL + l)*DH + dd) = rv;
        }
    }
}

// ---------------------------------------------------------------------------
// Fuzzy attention, one (b,h,64-row q-tile) per block.
// Scores = muQ.muK/64 in [0,1] -> exp without max subtraction is safe.
// Single pass over K/V chunks (TK=32), un-normalized O accumulate, normalize
// by row-sum at the end. Writes AO in row-major [b*L, H*DH] (ready for Wo).
// ---------------------------------------------------------------------------
__global__ __launch_bounds__(256)
void attn_k(const float* __restrict__ Qm, const float* __restrict__ Km,
            const float* __restrict__ Vm, float* __restrict__ AO)
{
    __shared__ float Qs[64][68];
    __shared__ float Ks[TK][68];
    __shared__ float Vs[TK][68];
    __shared__ float Es[64][TK + 4];
    __shared__ float rs[64];
    const int tid = threadIdx.x;
    const int ty = tid >> 4, tx = tid & 15;
    const int qt = blockIdx.x, h = blockIdx.y, b = blockIdx.z;
    const size_t headoff = ((size_t)(b*NH + h)) * SL * DH;
    const float* Qg = Qm + headoff + (size_t)qt * 64 * DH;

    #pragma unroll
    for (int r = 0; r < 4; ++r) {
        const int f = tid + 256*r;
        const int row = f >> 4, d4 = (f & 15) * 4;
        *(float4*)&Qs[row][d4] = *(const float4*)(Qg + row*DH + d4);
    }
    if (tid < 64) rs[tid] = 0.f;

    float o[4][4] = {};
    for (int kc = 0; kc < SL/TK; ++kc) {
        __syncthreads();
        #pragma unroll
        for (int r = 0; r < 2; ++r) {
            const int f = tid + 256*r;
            const int row = f >> 4, d4 = (f & 15) * 4;
            *(float4*)&Ks[row][d4] =
                *(const float4*)(Km + headoff + (size_t)(kc*TK + row)*DH + d4);
            *(float4*)&Vs[row][d4] =
                *(const float4*)(Vm + headoff + (size_t)(kc*TK + row)*DH + d4);
        }
        __syncthreads();
        // scores S[q=ty+16i][k=tx+16j], j<2
        float s[4][2] = {};
        #pragma unroll
        for (int d4 = 0; d4 < 16; ++d4) {
            float4 qv[4], kv[2];
            #pragma unroll
            for (int i = 0; i < 4; ++i) qv[i] = *(const float4*)&Qs[ty+16*i][4*d4];
            #pragma unroll
            for (int j = 0; j < 2; ++j) kv[j] = *(const float4*)&Ks[tx+16*j][4*d4];
            #pragma unroll
            for (int i = 0; i < 4; ++i)
                #pragma unroll
                for (int j = 0; j < 2; ++j)
                    s[i][j] += qv[i].x*kv[j].x + qv[i].y*kv[j].y
                             + qv[i].z*kv[j].z + qv[i].w*kv[j].w;
        }
        #pragma unroll
        for (int i = 0; i < 4; ++i) {
            float part = 0.f;
            #pragma unroll
            for (int j = 0; j < 2; ++j) {
                const float e = __expf(s[i][j] * 0.015625f);  // /64
                Es[ty+16*i][tx+16*j] = e;
                part += e;
            }
            #pragma unroll
            for (int off = 8; off; off >>= 1) part += __shfl_down(part, off, 16);
            if (tx == 0) rs[ty+16*i] += part;   // unique (ty,i) owner, no race
        }
        __syncthreads();
        // O += Es @ Vs
        #pragma unroll 8
        for (int k = 0; k < TK; ++k) {
            float ei[4], vj[4];
            #pragma unroll
            for (int i = 0; i < 4; ++i) ei[i] = Es[ty+16*i][k];
            #pragma unroll
            for (int j = 0; j < 4; ++j) vj[j] = Vs[k][tx+16*j];
            #pragma unroll
            for (int i = 0; i < 4; ++i)
                #pragma unroll
                for (int j = 0; j < 4; ++j)
                    o[i][j] += ei[i] * vj[j];
        }
    }
    float inv[4];
    #pragma unroll
    for (int i = 0; i < 4; ++i) inv[i] = 1.f / rs[ty+16*i];
    const size_t outbase = ((size_t)(b*SL + qt*64)) * DM + h*DH;
    #pragma unroll
    for (int i = 0; i < 4; ++i)
        #pragma unroll
        for (int j = 0; j < 4; ++j)
            AO[outbase + (size_t)(ty+16*i)*DM + tx + 16*j] = o[i][j] * inv[i];
}

// ---------------------------------------------------------------------------
// avg_attn = mean over heads of softmax(muQ muK^T / 64), direction 1 only.
// One block per (b, 16-row q-tile); loops all 16 heads in-block so the head
// average accumulates in registers (no atomics, no giant score buffer).
// ---------------------------------------------------------------------------
__global__ __launch_bounds__(256)
void avg_k(const float* __restrict__ Qm, const float* __restrict__ Km,
           float* __restrict__ avga)
{
    __shared__ float Qs[16][65];
    __shared__ float Ks[64][65];
    __shared__ float Es[16][520];
    __shared__ float rs[16];
    const int tid = threadIdx.x;
    const int qt = blockIdx.x, b = blockIdx.y;
    float acc[32];
    #pragma unroll
    for (int t = 0; t < 32; ++t) acc[t] = 0.f;

    for (int h = 0; h < NH; ++h) {
        __syncthreads();
        const size_t headoff = ((size_t)(b*NH + h)) * SL * DH;
        {
            const int row = tid >> 4; const int d4 = (tid & 15) * 4;
            const float4 v = *(const float4*)(Qm + headoff + (size_t)(qt*16 + row)*DH + d4);
            Qs[row][d4+0]=v.x; Qs[row][d4+1]=v.y; Qs[row][d4+2]=v.z; Qs[row][d4+3]=v.w;
        }
        if (tid < 16) rs[tid] = 0.f;
        for (int kc = 0; kc < 8; ++kc) {
            __syncthreads();
            #pragma unroll
            for (int r = 0; r < 4; ++r) {
                const int f = tid + 256*r;
                const int row = f >> 4; const int d4 = (f & 15) * 4;
                const float4 v = *(const float4*)(Km + headoff + (size_t)(kc*64 + row)*DH + d4);
                Ks[row][d4+0]=v.x; Ks[row][d4+1]=v.y; Ks[row][d4+2]=v.z; Ks[row][d4+3]=v.w;
            }
            __syncthreads();
            #pragma unroll
            for (int r = 0; r < 4; ++r) {
                const int q = (tid + 256*r) >> 6;   // all 64 lanes of a wave share q
                const int k = tid & 63;
                float s = 0.f;
                #pragma unroll 8
                for (int d = 0; d < 64; ++d) s += Qs[q][d] * Ks[k][d];
                const float e = __expf(s * 0.015625f);
                Es[q][kc*64 + k] = e;
                float p = e;
                #pragma unroll
                for (int off = 32; off; off >>= 1) p += __shfl_down(p, off, 64);
                if ((tid & 63) == 0) rs[q] += p;    // one owner lane per (q)
            }
        }
        __syncthreads();
        #pragma unroll
        for (int t = 0; t < 32; ++t) {
            const int idx = tid + 256*t;
            const int q = idx >> 9, j = idx & 511;
            acc[t] += Es[q][j] * (0.0625f / rs[q]);
        }
    }
    #pragma unroll
    for (int t = 0; t < 32; ++t) {
        const int idx = tid + 256*t;
        const int q = idx >> 9, j = idx & 511;
        avga[((size_t)(b*SL + qt*16 + q)) * SL + j] = acc[t];
    }
}

// ---------------------------------------------------------------------------
extern "C" void kernel_launch(void* const* d_in, const int* in_sizes, int n_in,
                              void* d_out, int out_size, void* d_ws, size_t ws_size,
                              hipStream_t stream)
{
    (void)in_sizes; (void)n_in; (void)out_size; (void)ws_size;
    const float* text  = (const float*)d_in[0];
    const float* image = (const float*)d_in[1];
    const float* Wq = (const float*)d_in[2];
    const float* bq = (const float*)d_in[3];
    const float* Wk = (const float*)d_in[4];
    const float* bk = (const float*)d_in[5];
    const float* Wv = (const float*)d_in[6];
    const float* bv = (const float*)d_in[7];
    const float* Wo = (const float*)d_in[8];
    const float* bo = (const float*)d_in[9];
    const float* W1 = (const float*)d_in[10];
    const float* b1 = (const float*)d_in[11];
    const float* W2 = (const float*)d_in[12];
    const float* b2 = (const float*)d_in[13];
    float* out = (float*)d_out;

    const size_t SZ = (size_t)NB * SL * DM;       // 4,194,304 floats
    // 5 rotating workspace buffers -> peak ws use = 84 MB
    float* P0 = (float*)d_ws;
    float* P1 = P0 + SZ;
    float* P2 = P1 + SZ;
    float* P3 = P2 + SZ;   // AOt
    float* P4 = P3 + SZ;   // AOi

    float* text_cross  = out;
    float* image_cross = out + SZ;
    float* comp        = out + 2*SZ;
    float* avga        = out + 3*SZ;

    const dim3 blk(256);
    const dim3 gg(16, 64);          // n-tiles × m-tiles
    const dim3 ag(SL/64, NH, NB);   // attention

    // ---- direction 1: Q from text, K/V from image ----
    gemm_k<1,1><<<gg, blk, 0, stream>>>(text,  text,  text,  DM, DM, DM, Wq, bq, P0); // muQ_t
    gemm_k<1,1><<<gg, blk, 0, stream>>>(image, image, image, DM, DM, DM, Wk, bk, P1); // muK_i
    gemm_k<0,1><<<gg, blk, 0, stream>>>(image, image, image, DM, DM, DM, Wv, bv, P2); // V_i
    attn_k<<<ag, blk, 0, stream>>>(P0, P1, P2, P3);                                   // AOt
    avg_k<<<dim3(SL/16, NB), blk, 0, stream>>>(P0, P1, avga);                         // avg_attn

    // ---- direction 2: Q from image, K/V from text (reuse P0..P2) ----
    gemm_k<1,1><<<gg, blk, 0, stream>>>(image, image, image, DM, DM, DM, Wq, bq, P0); // muQ_i
    gemm_k<1,1><<<gg, blk, 0, stream>>>(text,  text,  text,  DM, DM, DM, Wk, bk, P1); // muK_t
    gemm_k<0,1><<<gg, blk, 0, stream>>>(text,  text,  text,  DM, DM, DM, Wv, bv, P2); // V_t
    attn_k<<<ag, blk, 0, stream>>>(P0, P1, P2, P4);                                   // AOi

    // ---- output projections ----
    gemm_k<0,0><<<gg, blk, 0, stream>>>(P3, P3, P3, DM, DM, DM, Wo, bo, text_cross);
    gemm_k<0,0><<<gg, blk, 0, stream>>>(P4, P4, P4, DM, DM, DM, Wo, bo, image_cross);

    // ---- MLP: concat(text, image, text_cross) @ W1 -> relu -> @ W2 ----
    gemm_k<2,0><<<gg, blk, 0, stream>>>(text, image, text_cross, DM, 2*DM, 3*DM, W1, b1, P0);
    gemm_k<0,0><<<gg, blk, 0, stream>>>(P0, P0, P0, DM, DM, DM, W2, b2, comp);
}

// Round 2
// 2249.017 us; speedup vs baseline: 1.1806x; 1.1806x over previous
//
#include <hip/hip_runtime.h>

#define NB 8
#define SL 512
#define DM 1024
#define NH 16
#define DH 64
#define TK 32

// ---------------------------------------------------------------------------
// Generic tiled SGEMM: out[m,n] = ACT( sum_k A[m,k]*W[k,n] + bias[n] )
// A may be a k-concat of up to 3 sources (each row-stride DM).
// OUTMODE 0: row-major [4096,1024]; OUTMODE 1: [b,h,l,d] scatter (per-head).
// ACT: 0 none, 1 sigmoid, 2 relu.
// ---------------------------------------------------------------------------
template<int ACT, int OUTMODE>
__global__ __launch_bounds__(256)
void gemm_k(const float* __restrict__ A0, const float* __restrict__ A1,
            const float* __restrict__ A2,
            const int K1, const int K2, const int Ktot,
            const float* __restrict__ W, const float* __restrict__ bias,
            float* __restrict__ out)
{
    __shared__ float As[16][68];   // [k][m], padded
    __shared__ float Bs[16][68];   // [k][n], padded
    const int tid = threadIdx.x;
    const int ty = tid >> 4, tx = tid & 15;
    const int m0 = blockIdx.y * 64;
    const int n0 = blockIdx.x * 64;
    const int mA = tid >> 2;            // 0..63
    const int kA = (tid & 3) * 4;       // 0,4,8,12
    const int kB = tid >> 4;            // 0..15
    const int nB = (tid & 15) * 4;      // 0..60

    float acc[4][4] = {};
    for (int k0 = 0; k0 < Ktot; k0 += 16) {
        const int kk = k0 + kA;
        const float* src; int ko;
        if (kk < K1)      { src = A0; ko = kk; }
        else if (kk < K2) { src = A1; ko = kk - K1; }
        else              { src = A2; ko = kk - K2; }
        const float4 av = *(const float4*)(src + (size_t)(m0 + mA) * DM + ko);
        const float4 bv = *(const float4*)(W + (size_t)(k0 + kB) * DM + n0 + nB);
        __syncthreads();
        As[kA+0][mA] = av.x; As[kA+1][mA] = av.y;
        As[kA+2][mA] = av.z; As[kA+3][mA] = av.w;
        *(float4*)&Bs[kB][nB] = bv;
        __syncthreads();
        #pragma unroll
        for (int k = 0; k < 16; ++k) {
            const float4 a  = *(const float4*)&As[k][4*ty];
            const float4 b4 = *(const float4*)&Bs[k][4*tx];
            const float aa[4] = {a.x, a.y, a.z, a.w};
            const float bb[4] = {b4.x, b4.y, b4.z, b4.w};
            #pragma unroll
            for (int i = 0; i < 4; ++i)
                #pragma unroll
                for (int j = 0; j < 4; ++j)
                    acc[i][j] += aa[i] * bb[j];
        }
    }

    const int nb = n0 + 4*tx;
    const float4 bi = *(const float4*)(bias + nb);
    const float bias4[4] = {bi.x, bi.y, bi.z, bi.w};
    #pragma unroll
    for (int i = 0; i < 4; ++i) {
        const int m = m0 + 4*ty + i;
        float r[4];
        #pragma unroll
        for (int j = 0; j < 4; ++j) {
            float v = acc[i][j] + bias4[j];
            if (ACT == 1)      v = 1.f / (1.f + __expf(-v));
            else if (ACT == 2) v = v > 0.f ? v : 0.f;
            r[j] = v;
        }
        const float4 rv = {r[0], r[1], r[2], r[3]};
        if (OUTMODE == 0) {
            *(float4*)(out + (size_t)m * DM + nb) = rv;
        } else {
            const int bb_ = m >> 9, l = m & 511;
            const int hh  = nb >> 6, dd = nb & 63;
            *(float4*)(out + ((size_t)(bb_*NH + hh)*SL + l)*DH + dd) = rv;
        }
    }
}

// ---------------------------------------------------------------------------
// Fuzzy attention, one (b,h,64-row q-tile) per block.
// Scores = muQ.muK/64 in [0,1] -> exp without max subtraction is safe.
// Writes AO row-major [b*L, H*DH]; also exports softmax row-sums to RS
// (consumed by avg2_k for the head-averaged attention output).
// ---------------------------------------------------------------------------
__global__ __launch_bounds__(256)
void attn_k(const float* __restrict__ Qm, const float* __restrict__ Km,
            const float* __restrict__ Vm, float* __restrict__ AO,
            float* __restrict__ RS)
{
    __shared__ float Qs[64][68];
    __shared__ float Ks[TK][68];
    __shared__ float Vs[TK][68];
    __shared__ float Es[64][TK + 4];
    __shared__ float rs[64];
    const int tid = threadIdx.x;
    const int ty = tid >> 4, tx = tid & 15;
    const int qt = blockIdx.x, h = blockIdx.y, b = blockIdx.z;
    const size_t headoff = ((size_t)(b*NH + h)) * SL * DH;
    const float* Qg = Qm + headoff + (size_t)qt * 64 * DH;

    #pragma unroll
    for (int r = 0; r < 4; ++r) {
        const int f = tid + 256*r;
        const int row = f >> 4, d4 = (f & 15) * 4;
        *(float4*)&Qs[row][d4] = *(const float4*)(Qg + row*DH + d4);
    }
    if (tid < 64) rs[tid] = 0.f;

    float o[4][4] = {};
    for (int kc = 0; kc < SL/TK; ++kc) {
        __syncthreads();
        #pragma unroll
        for (int r = 0; r < 2; ++r) {
            const int f = tid + 256*r;
            const int row = f >> 4, d4 = (f & 15) * 4;
            *(float4*)&Ks[row][d4] =
                *(const float4*)(Km + headoff + (size_t)(kc*TK + row)*DH + d4);
            *(float4*)&Vs[row][d4] =
                *(const float4*)(Vm + headoff + (size_t)(kc*TK + row)*DH + d4);
        }
        __syncthreads();
        // scores S[q=ty+16i][k=tx+16j], j<2
        float s[4][2] = {};
        #pragma unroll
        for (int d4 = 0; d4 < 16; ++d4) {
            float4 qv[4], kv[2];
            #pragma unroll
            for (int i = 0; i < 4; ++i) qv[i] = *(const float4*)&Qs[ty+16*i][4*d4];
            #pragma unroll
            for (int j = 0; j < 2; ++j) kv[j] = *(const float4*)&Ks[tx+16*j][4*d4];
            #pragma unroll
            for (int i = 0; i < 4; ++i)
                #pragma unroll
                for (int j = 0; j < 2; ++j)
                    s[i][j] += qv[i].x*kv[j].x + qv[i].y*kv[j].y
                             + qv[i].z*kv[j].z + qv[i].w*kv[j].w;
        }
        #pragma unroll
        for (int i = 0; i < 4; ++i) {
            float part = 0.f;
            #pragma unroll
            for (int j = 0; j < 2; ++j) {
                const float e = __expf(s[i][j] * 0.015625f);  // /64
                Es[ty+16*i][tx+16*j] = e;
                part += e;
            }
            #pragma unroll
            for (int off = 8; off; off >>= 1) part += __shfl_down(part, off, 16);
            if (tx == 0) rs[ty+16*i] += part;   // unique (ty,i) owner, no race
        }
        __syncthreads();
        // O += Es @ Vs
        #pragma unroll 8
        for (int k = 0; k < TK; ++k) {
            float ei[4], vj[4];
            #pragma unroll
            for (int i = 0; i < 4; ++i) ei[i] = Es[ty+16*i][k];
            #pragma unroll
            for (int j = 0; j < 4; ++j) vj[j] = Vs[k][tx+16*j];
            #pragma unroll
            for (int i = 0; i < 4; ++i)
                #pragma unroll
                for (int j = 0; j < 4; ++j)
                    o[i][j] += ei[i] * vj[j];
        }
    }
    // export row sums for avg2_k (dir-1 consumer; dir-2 write is harmless)
    if (tid < 64) RS[(size_t)(b*NH + h)*SL + qt*64 + tid] = rs[tid];

    float inv[4];
    #pragma unroll
    for (int i = 0; i < 4; ++i) inv[i] = 1.f / rs[ty+16*i];
    const size_t outbase = ((size_t)(b*SL + qt*64)) * DM + h*DH;
    #pragma unroll
    for (int i = 0; i < 4; ++i)
        #pragma unroll
        for (int j = 0; j < 4; ++j)
            AO[outbase + (size_t)(ty+16*i)*DM + tx + 16*j] = o[i][j] * inv[i];
}

// ---------------------------------------------------------------------------
// avg_attn = mean over heads of softmax(muQ muK^T / 64), direction 1 only.
// Register-tiled recompute: one block per (k-tile, q-tile, b) 64x64 output
// tile, looping all 16 heads. Row-sums come precomputed from attn_k via RS.
// float4 LDS reads + 4x4 accumulation: 8 ds_read_b128 per 64 FMA (the old
// avg_k did 128 ds_read_b32 per 64 FMA -> LDS-issue bound at 550 us).
// ---------------------------------------------------------------------------
__global__ __launch_bounds__(256)
void avg2_k(const float* __restrict__ Qm, const float* __restrict__ Km,
            const float* __restrict__ RS, float* __restrict__ avga)
{
    __shared__ float Qs[64][68];
    __shared__ float Ks[64][68];
    __shared__ float rss[64];
    const int tid = threadIdx.x;
    const int ty = tid >> 4, tx = tid & 15;
    const int kt = blockIdx.x, qt = blockIdx.y, b = blockIdx.z;

    float acc[4][4] = {};
    for (int h = 0; h < NH; ++h) {
        const size_t headoff = ((size_t)(b*NH + h)) * SL * DH;
        __syncthreads();   // previous head's compute must finish before overwrite
        #pragma unroll
        for (int r = 0; r < 4; ++r) {
            const int f = tid + 256*r;
            const int row = f >> 4, d4 = (f & 15) * 4;
            *(float4*)&Qs[row][d4] =
                *(const float4*)(Qm + headoff + (size_t)(qt*64 + row)*DH + d4);
            *(float4*)&Ks[row][d4] =
                *(const float4*)(Km + headoff + (size_t)(kt*64 + row)*DH + d4);
        }
        if (tid < 64) rss[tid] = RS[(size_t)(b*NH + h)*SL + qt*64 + tid];
        __syncthreads();

        float s[4][4] = {};
        #pragma unroll
        for (int d4 = 0; d4 < 16; ++d4) {
            float4 qv[4], kv[4];
            #pragma unroll
            for (int i = 0; i < 4; ++i) qv[i] = *(const float4*)&Qs[ty+16*i][4*d4];
            #pragma unroll
            for (int j = 0; j < 4; ++j) kv[j] = *(const float4*)&Ks[tx+16*j][4*d4];
            #pragma unroll
            for (int i = 0; i < 4; ++i)
                #pragma unroll
                for (int j = 0; j < 4; ++j)
                    s[i][j] += qv[i].x*kv[j].x + qv[i].y*kv[j].y
                             + qv[i].z*kv[j].z + qv[i].w*kv[j].w;
        }
        #pragma unroll
        for (int i = 0; i < 4; ++i) {
            const float ir = 0.0625f / rss[ty+16*i];   // /16 heads folded in
            #pragma unroll
            for (int j = 0; j < 4; ++j)
                acc[i][j] += __expf(s[i][j] * 0.015625f) * ir;
        }
    }
    #pragma unroll
    for (int i = 0; i < 4; ++i)
        #pragma unroll
        for (int j = 0; j < 4; ++j)
            avga[((size_t)(b*SL + qt*64 + ty+16*i))*SL + kt*64 + tx+16*j] = acc[i][j];
}

// ---------------------------------------------------------------------------
extern "C" void kernel_launch(void* const* d_in, const int* in_sizes, int n_in,
                              void* d_out, int out_size, void* d_ws, size_t ws_size,
                              hipStream_t stream)
{
    (void)in_sizes; (void)n_in; (void)out_size; (void)ws_size;
    const float* text  = (const float*)d_in[0];
    const float* image = (const float*)d_in[1];
    const float* Wq = (const float*)d_in[2];
    const float* bq = (const float*)d_in[3];
    const float* Wk = (const float*)d_in[4];
    const float* bk = (const float*)d_in[5];
    const float* Wv = (const float*)d_in[6];
    const float* bv = (const float*)d_in[7];
    const float* Wo = (const float*)d_in[8];
    const float* bo = (const float*)d_in[9];
    const float* W1 = (const float*)d_in[10];
    const float* b1 = (const float*)d_in[11];
    const float* W2 = (const float*)d_in[12];
    const float* b2 = (const float*)d_in[13];
    float* out = (float*)d_out;

    const size_t SZ = (size_t)NB * SL * DM;       // 4,194,304 floats
    float* P0 = (float*)d_ws;
    float* P1 = P0 + SZ;
    float* P2 = P1 + SZ;
    float* P3 = P2 + SZ;   // AOt
    float* P4 = P3 + SZ;   // AOi
    float* RS = P4 + SZ;   // softmax row sums, NB*NH*SL floats (262 KB)

    float* text_cross  = out;
    float* image_cross = out + SZ;
    float* comp        = out + 2*SZ;
    float* avga        = out + 3*SZ;

    const dim3 blk(256);
    const dim3 gg(16, 64);          // n-tiles × m-tiles
    const dim3 ag(SL/64, NH, NB);   // attention

    // ---- direction 1: Q from text, K/V from image ----
    gemm_k<1,1><<<gg, blk, 0, stream>>>(text,  text,  text,  DM, DM, DM, Wq, bq, P0); // muQ_t
    gemm_k<1,1><<<gg, blk, 0, stream>>>(image, image, image, DM, DM, DM, Wk, bk, P1); // muK_i
    gemm_k<0,1><<<gg, blk, 0, stream>>>(image, image, image, DM, DM, DM, Wv, bv, P2); // V_i
    attn_k<<<ag, blk, 0, stream>>>(P0, P1, P2, P3, RS);                               // AOt + RS
    avg2_k<<<dim3(SL/64, SL/64, NB), blk, 0, stream>>>(P0, P1, RS, avga);             // avg_attn

    // ---- direction 2: Q from image, K/V from text (reuse P0..P2) ----
    gemm_k<1,1><<<gg, blk, 0, stream>>>(image, image, image, DM, DM, DM, Wq, bq, P0); // muQ_i
    gemm_k<1,1><<<gg, blk, 0, stream>>>(text,  text,  text,  DM, DM, DM, Wk, bk, P1); // muK_t
    gemm_k<0,1><<<gg, blk, 0, stream>>>(text,  text,  text,  DM, DM, DM, Wv, bv, P2); // V_t
    attn_k<<<ag, blk, 0, stream>>>(P0, P1, P2, P4, RS);                               // AOi

    // ---- output projections ----
    gemm_k<0,0><<<gg, blk, 0, stream>>>(P3, P3, P3, DM, DM, DM, Wo, bo, text_cross);
    gemm_k<0,0><<<gg, blk, 0, stream>>>(P4, P4, P4, DM, DM, DM, Wo, bo, image_cross);

    // ---- MLP: concat(text, image, text_cross) @ W1 -> relu -> @ W2 ----
    gemm_k<2,0><<<gg, blk, 0, stream>>>(text, image, text_cross, DM, 2*DM, 3*DM, W1, b1, P0);
    gemm_k<0,0><<<gg, blk, 0, stream>>>(P0, P0, P0, DM, DM, DM, W2, b2, comp);
}

// Round 3
// 1076.594 us; speedup vs baseline: 2.4663x; 2.0890x over previous
//
#include <hip/hip_runtime.h>

#define NB 8
#define SL 512
#define DM 1024
#define NH 16
#define DH 64
#define TK 32

using bfrag = __attribute__((ext_vector_type(8))) short;   // 8 bf16 (4 VGPRs)
using facc  = __attribute__((ext_vector_type(4))) float;   // 4 fp32 acc

__device__ __forceinline__ float bf2f(ushort u) {
    return __uint_as_float(((unsigned)u) << 16);
}
__device__ __forceinline__ ushort f2bf(float f) {
    unsigned x = __float_as_uint(f);
    return (ushort)((x + 0x7FFFu + ((x >> 16) & 1u)) >> 16);   // RNE
}
__device__ __forceinline__ float4 bf4_f4(ushort4 u) {
    return make_float4(bf2f(u.x), bf2f(u.y), bf2f(u.z), bf2f(u.w));
}
__device__ __forceinline__ unsigned pack2(float a, float b) {
    return (unsigned)f2bf(a) | ((unsigned)f2bf(b) << 16);
}
__device__ __forceinline__ void gload16(const ushort* g, ushort* l) {
    __builtin_amdgcn_global_load_lds(
        (const __attribute__((address_space(1))) unsigned*)g,
        (__attribute__((address_space(3))) unsigned*)l, 16, 0, 0);
}

// ---------------------------------------------------------------------------
// fp32 -> bf16 convert (4 elems/thread)
// ---------------------------------------------------------------------------
__global__ __launch_bounds__(256)
void cvt_k(const float* __restrict__ s, ushort* __restrict__ d) {
    const size_t i = (size_t)(blockIdx.x * 256 + threadIdx.x) * 4;
    const float4 f = *(const float4*)(s + i);
    *(ushort4*)(d + i) = make_ushort4(f2bf(f.x), f2bf(f.y), f2bf(f.z), f2bf(f.w));
}

// ---------------------------------------------------------------------------
// Transpose-convert: W[R,C] fp32 -> WT[C,R] bf16. grid (C/64, R/64).
// ---------------------------------------------------------------------------
__global__ __launch_bounds__(256)
void tconv_k(const float* __restrict__ W, ushort* __restrict__ WT,
             const int R, const int C) {
    __shared__ ushort T[64][68];
    const int tid = threadIdx.x;
    const int c0 = blockIdx.x * 64, r0 = blockIdx.y * 64;
    #pragma unroll
    for (int rr = 0; rr < 4; ++rr) {
        const int r = (tid >> 4) + rr * 16;
        const int c4 = (tid & 15) * 4;
        const float4 f = *(const float4*)(W + (size_t)(r0 + r) * C + c0 + c4);
        T[c4+0][r] = f2bf(f.x); T[c4+1][r] = f2bf(f.y);
        T[c4+2][r] = f2bf(f.z); T[c4+3][r] = f2bf(f.w);
    }
    __syncthreads();
    #pragma unroll
    for (int rr = 0; rr < 4; ++rr) {
        const int c = (tid >> 4) + rr * 16;
        const int r4 = (tid & 15) * 4;
        *(ushort4*)(WT + (size_t)(c0 + c) * R + r0 + r4) =
            make_ushort4(T[c][r4+0], T[c][r4+1], T[c][r4+2], T[c][r4+3]);
    }
}

// ---------------------------------------------------------------------------
// bf16 MFMA GEMM, m97 structure: 128x128 tile, 4 waves (2x2 of 64x64), BK=64,
// global_load_lds width-16 staging, mfma_f32_16x16x32_bf16.
//   out[m,n] = ACT( sum_k A[m,k]*B[k,n] + bias[n] ),  B given as BT[n,k].
// A is a K-concat: k<KA1 from A0, k<KA2 from A1 (bf16), else from A2f (fp32,
// converted during staging). All dims multiples of tile sizes.
// OMODE 0: fp32 row-major (stride DM). 1: bf16 scatter [g,h,l,d] (g=m>>9).
// 2: bf16 row-major (stride DM).  ACT: 0 none, 1 sigmoid, 2 relu.
// ---------------------------------------------------------------------------
template<int ACT, int OMODE>
__global__ __launch_bounds__(256, 2)
void mfma_gemm(const ushort* __restrict__ A0, const ushort* __restrict__ A1,
               const float* __restrict__ A2f,
               const int KA1, const int KA2, const int Ktot,
               const int lda, const int ldaf,
               const ushort* __restrict__ BT, const int ldb,
               const float* __restrict__ bias,
               float* __restrict__ outf, ushort* __restrict__ outb)
{
    __shared__ ushort As[128 * 64];   // [m][k] row-major, 16 KB
    __shared__ ushort Bs[128 * 64];   // [n][k] row-major (B^T tile), 16 KB
    const int tid  = threadIdx.x;
    const int w    = tid >> 6;
    const int lane = tid & 63;
    const int ln   = lane & 15, qd = lane >> 4;
    const int wm = (w & 1) * 64, wn = (w >> 1) * 64;
    const int m0 = blockIdx.y * 128, n0 = blockIdx.x * 128;

    const int arow = (lane >> 3);        // row-in-chunk 0..7
    const int kc8  = (lane & 7) * 8;     // k offset (8 bf16 = 16 B)

    facc acc[4][4];
    #pragma unroll
    for (int i = 0; i < 4; ++i)
        #pragma unroll
        for (int j = 0; j < 4; ++j)
            acc[i][j] = (facc){0.f, 0.f, 0.f, 0.f};

    for (int k0 = 0; k0 < Ktot; k0 += 64) {
        __syncthreads();   // previous iteration's frag reads done
        // ---- stage B (always bf16 async) ----
        #pragma unroll
        for (int t = 0; t < 4; ++t) {
            const int c = w * 4 + t;
            gload16(BT + (size_t)(n0 + c * 8 + arow) * ldb + k0 + kc8,
                    &Bs[c * 512]);
        }
        // ---- stage A ----
        if (k0 < KA2) {
            const ushort* Ab; int ko;
            if (k0 < KA1) { Ab = A0; ko = k0; }
            else          { Ab = A1; ko = k0 - KA1; }
            #pragma unroll
            for (int t = 0; t < 4; ++t) {
                const int c = w * 4 + t;
                gload16(Ab + (size_t)(m0 + c * 8 + arow) * lda + ko + kc8,
                        &As[c * 512]);
            }
        } else {           // fp32 source: load + convert + ds_write
            const int ko = k0 - KA2;
            #pragma unroll
            for (int t = 0; t < 4; ++t) {
                const int c = w * 4 + t;
                const float* src = A2f + (size_t)(m0 + c * 8 + arow) * ldaf + ko + kc8;
                const float4 f0 = *(const float4*)src;
                const float4 f1 = *(const float4*)(src + 4);
                uint4 p;
                p.x = pack2(f0.x, f0.y); p.y = pack2(f0.z, f0.w);
                p.z = pack2(f1.x, f1.y); p.w = pack2(f1.z, f1.w);
                *(uint4*)&As[c * 512 + lane * 8] = p;
            }
        }
        __syncthreads();   // drains vmcnt (global_load_lds) + lgkmcnt

        #pragma unroll
        for (int ks = 0; ks < 2; ++ks) {
            bfrag af[4], bfv[4];
            #pragma unroll
            for (int i = 0; i < 4; ++i)
                af[i] = *(const bfrag*)&As[(wm + i*16 + ln) * 64 + ks*32 + qd*8];
            #pragma unroll
            for (int j = 0; j < 4; ++j)
                bfv[j] = *(const bfrag*)&Bs[(wn + j*16 + ln) * 64 + ks*32 + qd*8];
            #pragma unroll
            for (int i = 0; i < 4; ++i)
                #pragma unroll
                for (int j = 0; j < 4; ++j)
                    acc[i][j] = __builtin_amdgcn_mfma_f32_16x16x32_bf16(
                        af[i], bfv[j], acc[i][j], 0, 0, 0);
        }
    }

    // ---- epilogue: C/D layout col=lane&15, row=qd*4+r ----
    #pragma unroll
    for (int j = 0; j < 4; ++j) {
        const int n = n0 + wn + j * 16 + ln;
        const float bn = bias[n];
        #pragma unroll
        for (int i = 0; i < 4; ++i) {
            const int mb = m0 + wm + i * 16 + qd * 4;
            #pragma unroll
            for (int r = 0; r < 4; ++r) {
                float v = acc[i][j][r] + bn;
                if (ACT == 1)      v = 1.f / (1.f + __expf(-v));
                else if (ACT == 2) v = v > 0.f ? v : 0.f;
                const int m = mb + r;
                if (OMODE == 0) {
                    outf[(size_t)m * DM + n] = v;
                } else if (OMODE == 1) {
                    const int g = m >> 9, l = m & 511;
                    const int h = n >> 6, d = n & 63;
                    outb[(((size_t)(g * NH + h)) * SL + l) * DH + d] = f2bf(v);
                } else {
                    outb[(size_t)m * DM + n] = f2bf(v);
                }
            }
        }
    }
}

// ---------------------------------------------------------------------------
// Fuzzy attention (bf16 Q/K/V in [g,h,l,d], fp32 compute, bf16 AO out).
// Scores in [0,1] -> exp without max subtraction. Exports softmax row sums.
// ---------------------------------------------------------------------------
__global__ __launch_bounds__(256)
void attn_k(const ushort* __restrict__ Qm, const ushort* __restrict__ Km,
            const ushort* __restrict__ Vm, ushort* __restrict__ AO,
            float* __restrict__ RS)
{
    __shared__ float Qs[64][68];
    __shared__ float Ks[TK][68];
    __shared__ float Vs[TK][68];
    __shared__ float Es[64][TK + 4];
    __shared__ float rs[64];
    const int tid = threadIdx.x;
    const int ty = tid >> 4, tx = tid & 15;
    const int qt = blockIdx.x, h = blockIdx.y, b = blockIdx.z;
    const size_t headoff = ((size_t)(b*NH + h)) * SL * DH;
    const ushort* Qg = Qm + headoff + (size_t)qt * 64 * DH;

    #pragma unroll
    for (int r = 0; r < 4; ++r) {
        const int f = tid + 256*r;
        const int row = f >> 4, d4 = (f & 15) * 4;
        *(float4*)&Qs[row][d4] = bf4_f4(*(const ushort4*)(Qg + row*DH + d4));
    }
    if (tid < 64) rs[tid] = 0.f;

    float o[4][4] = {};
    for (int kc = 0; kc < SL/TK; ++kc) {
        __syncthreads();
        #pragma unroll
        for (int r = 0; r < 2; ++r) {
            const int f = tid + 256*r;
            const int row = f >> 4, d4 = (f & 15) * 4;
            *(float4*)&Ks[row][d4] =
                bf4_f4(*(const ushort4*)(Km + headoff + (size_t)(kc*TK + row)*DH + d4));
            *(float4*)&Vs[row][d4] =
                bf4_f4(*(const ushort4*)(Vm + headoff + (size_t)(kc*TK + row)*DH + d4));
        }
        __syncthreads();
        float s[4][2] = {};
        #pragma unroll
        for (int d4 = 0; d4 < 16; ++d4) {
            float4 qv[4], kv[2];
            #pragma unroll
            for (int i = 0; i < 4; ++i) qv[i] = *(const float4*)&Qs[ty+16*i][4*d4];
            #pragma unroll
            for (int j = 0; j < 2; ++j) kv[j] = *(const float4*)&Ks[tx+16*j][4*d4];
            #pragma unroll
            for (int i = 0; i < 4; ++i)
                #pragma unroll
                for (int j = 0; j < 2; ++j)
                    s[i][j] += qv[i].x*kv[j].x + qv[i].y*kv[j].y
                             + qv[i].z*kv[j].z + qv[i].w*kv[j].w;
        }
        #pragma unroll
        for (int i = 0; i < 4; ++i) {
            float part = 0.f;
            #pragma unroll
            for (int j = 0; j < 2; ++j) {
                const float e = __expf(s[i][j] * 0.015625f);
                Es[ty+16*i][tx+16*j] = e;
                part += e;
            }
            #pragma unroll
            for (int off = 8; off; off >>= 1) part += __shfl_down(part, off, 16);
            if (tx == 0) rs[ty+16*i] += part;
        }
        __syncthreads();
        #pragma unroll 8
        for (int k = 0; k < TK; ++k) {
            float ei[4], vj[4];
            #pragma unroll
            for (int i = 0; i < 4; ++i) ei[i] = Es[ty+16*i][k];
            #pragma unroll
            for (int j = 0; j < 4; ++j) vj[j] = Vs[k][tx+16*j];
            #pragma unroll
            for (int i = 0; i < 4; ++i)
                #pragma unroll
                for (int j = 0; j < 4; ++j)
                    o[i][j] += ei[i] * vj[j];
        }
    }
    if (tid < 64) RS[(size_t)(b*NH + h)*SL + qt*64 + tid] = rs[tid];

    float inv[4];
    #pragma unroll
    for (int i = 0; i < 4; ++i) inv[i] = 1.f / rs[ty+16*i];
    const size_t outbase = ((size_t)(b*SL + qt*64)) * DM + h*DH;
    #pragma unroll
    for (int i = 0; i < 4; ++i)
        #pragma unroll
        for (int j = 0; j < 4; ++j)
            AO[outbase + (size_t)(ty+16*i)*DM + tx + 16*j] = f2bf(o[i][j] * inv[i]);
}

// ---------------------------------------------------------------------------
// avg_attn: mean over heads of softmax rows, recomputed from bf16 Q/K with
// precomputed row sums (RS). One 64x64 output tile per block, 16-head loop.
// ---------------------------------------------------------------------------
__global__ __launch_bounds__(256)
void avg2_k(const ushort* __restrict__ Qm, const ushort* __restrict__ Km,
            const float* __restrict__ RS, float* __restrict__ avga)
{
    __shared__ float Qs[64][68];
    __shared__ float Ks[64][68];
    __shared__ float rss[64];
    const int tid = threadIdx.x;
    const int ty = tid >> 4, tx = tid & 15;
    const int kt = blockIdx.x, qt = blockIdx.y, b = blockIdx.z;

    float acc[4][4] = {};
    for (int h = 0; h < NH; ++h) {
        const size_t headoff = ((size_t)(b*NH + h)) * SL * DH;
        __syncthreads();
        #pragma unroll
        for (int r = 0; r < 4; ++r) {
            const int f = tid + 256*r;
            const int row = f >> 4, d4 = (f & 15) * 4;
            *(float4*)&Qs[row][d4] =
                bf4_f4(*(const ushort4*)(Qm + headoff + (size_t)(qt*64 + row)*DH + d4));
            *(float4*)&Ks[row][d4] =
                bf4_f4(*(const ushort4*)(Km + headoff + (size_t)(kt*64 + row)*DH + d4));
        }
        if (tid < 64) rss[tid] = RS[(size_t)(b*NH + h)*SL + qt*64 + tid];
        __syncthreads();

        float s[4][4] = {};
        #pragma unroll
        for (int d4 = 0; d4 < 16; ++d4) {
            float4 qv[4], kv[4];
            #pragma unroll
            for (int i = 0; i < 4; ++i) qv[i] = *(const float4*)&Qs[ty+16*i][4*d4];
            #pragma unroll
            for (int j = 0; j < 4; ++j) kv[j] = *(const float4*)&Ks[tx+16*j][4*d4];
            #pragma unroll
            for (int i = 0; i < 4; ++i)
                #pragma unroll
                for (int j = 0; j < 4; ++j)
                    s[i][j] += qv[i].x*kv[j].x + qv[i].y*kv[j].y
                             + qv[i].z*kv[j].z + qv[i].w*kv[j].w;
        }
        #pragma unroll
        for (int i = 0; i < 4; ++i) {
            const float ir = 0.0625f / rss[ty+16*i];
            #pragma unroll
            for (int j = 0; j < 4; ++j)
                acc[i][j] += __expf(s[i][j] * 0.015625f) * ir;
        }
    }
    #pragma unroll
    for (int i = 0; i < 4; ++i)
        #pragma unroll
        for (int j = 0; j < 4; ++j)
            avga[((size_t)(b*SL + qt*64 + ty+16*i))*SL + kt*64 + tx+16*j] = acc[i][j];
}

// ---------------------------------------------------------------------------
extern "C" void kernel_launch(void* const* d_in, const int* in_sizes, int n_in,
                              void* d_out, int out_size, void* d_ws, size_t ws_size,
                              hipStream_t stream)
{
    (void)in_sizes; (void)n_in; (void)out_size; (void)ws_size;
    const float* text  = (const float*)d_in[0];
    const float* image = (const float*)d_in[1];
    const float* Wq = (const float*)d_in[2];
    const float* bq = (const float*)d_in[3];
    const float* Wk = (const float*)d_in[4];
    const float* bk = (const float*)d_in[5];
    const float* Wv = (const float*)d_in[6];
    const float* bv = (const float*)d_in[7];
    const float* Wo = (const float*)d_in[8];
    const float* bo = (const float*)d_in[9];
    const float* W1 = (const float*)d_in[10];
    const float* b1 = (const float*)d_in[11];
    const float* W2 = (const float*)d_in[12];
    const float* b2 = (const float*)d_in[13];
    float* out = (float*)d_out;

    const size_t SZ   = (size_t)NB * SL * DM;   // 4,194,304 (fp32 elems per tensor)
    const size_t HALF = SZ;                     // half of a [16,NH,SL,DH] bf16 buffer

    // ---- workspace layout (bf16 = ushort), total ~82.1 MB ----
    ushort* xbf = (ushort*)d_ws;        // [8192,1024] text rows 0..4095, image 4096..
    ushort* Qb  = xbf + 2*SZ;           // [16,NH,SL,DH] g=0..7 text, 8..15 image
    ushort* Kb  = Qb  + 2*SZ;
    ushort* Vb  = Kb  + 2*SZ;
    ushort* AOt = Vb  + 2*SZ;           // [4096,1024]
    ushort* Wt  = AOt + SZ;             // transposed-weight scratch (<= 6.3 MB)
    float*  RS  = (float*)(Wt + 3*DM*DM);   // [8,NH,SL]
    ushort* AOi    = Vb + HALF;         // reuses Vi (dead after attn dir-1)
    ushort* hidden = Qb;                // reuses Qt (dead after avg2)

    float* text_cross  = out;
    float* image_cross = out + SZ;
    float* comp        = out + 2*SZ;
    float* avga        = out + 3*SZ;

    const dim3 blk(256);
    const dim3 gQKV(8, 64);     // N=1024, M=8192 -> 512 blocks
    const dim3 gHALFM(8, 32);   // N=1024, M=4096 -> 256 blocks
    const dim3 ag(SL/64, NH, NB);

    // ---- convert activations to bf16 ----
    cvt_k<<<4096, blk, 0, stream>>>(text,  xbf);
    cvt_k<<<4096, blk, 0, stream>>>(image, xbf + SZ);

    // ---- Q/K/V projections (text+image batched along M) ----
    tconv_k<<<dim3(16,16), blk, 0, stream>>>(Wq, Wt,           DM, DM);
    tconv_k<<<dim3(16,16), blk, 0, stream>>>(Wk, Wt + DM*DM,   DM, DM);
    tconv_k<<<dim3(16,16), blk, 0, stream>>>(Wv, Wt + 2*DM*DM, DM, DM);
    mfma_gemm<1,1><<<gQKV, blk, 0, stream>>>(xbf, xbf, nullptr, DM, DM, DM, DM, DM,
                                             Wt,           DM, bq, nullptr, Qb);
    mfma_gemm<1,1><<<gQKV, blk, 0, stream>>>(xbf, xbf, nullptr, DM, DM, DM, DM, DM,
                                             Wt + DM*DM,   DM, bk, nullptr, Kb);
    mfma_gemm<0,1><<<gQKV, blk, 0, stream>>>(xbf, xbf, nullptr, DM, DM, DM, DM, DM,
                                             Wt + 2*DM*DM, DM, bv, nullptr, Vb);

    // ---- attention dir-1 (Q text, K/V image), avg_attn, dir-2 ----
    attn_k<<<ag, blk, 0, stream>>>(Qb, Kb + HALF, Vb + HALF, AOt, RS);
    avg2_k<<<dim3(SL/64, SL/64, NB), blk, 0, stream>>>(Qb, Kb + HALF, RS, avga);
    attn_k<<<ag, blk, 0, stream>>>(Qb + HALF, Kb, Vb, AOi, RS);

    // ---- output projections ----
    tconv_k<<<dim3(16,16), blk, 0, stream>>>(Wo, Wt, DM, DM);
    mfma_gemm<0,0><<<gHALFM, blk, 0, stream>>>(AOt, AOt, nullptr, DM, DM, DM, DM, DM,
                                               Wt, DM, bo, text_cross, nullptr);
    mfma_gemm<0,0><<<gHALFM, blk, 0, stream>>>(AOi, AOi, nullptr, DM, DM, DM, DM, DM,
                                               Wt, DM, bo, image_cross, nullptr);

    // ---- MLP: concat(text, image, text_cross) @ W1 -> relu -> @ W2 ----
    tconv_k<<<dim3(16,48), blk, 0, stream>>>(W1, Wt, 3*DM, DM);
    mfma_gemm<2,2><<<gHALFM, blk, 0, stream>>>(xbf, xbf + SZ, text_cross,
                                               DM, 2*DM, 3*DM, DM, DM,
                                               Wt, 3*DM, b1, nullptr, hidden);
    tconv_k<<<dim3(16,16), blk, 0, stream>>>(W2, Wt, DM, DM);
    mfma_gemm<0,0><<<gHALFM, blk, 0, stream>>>(hidden, hidden, nullptr, DM, DM, DM, DM, DM,
                                               Wt, DM, b2, comp, nullptr);
}

// Round 4
// 570.970 us; speedup vs baseline: 4.6504x; 1.8856x over previous
//
#include <hip/hip_runtime.h>

#define NB 8
#define SL 512
#define DM 1024
#define NH 16
#define DH 64

using bfrag = __attribute__((ext_vector_type(8))) short;   // 8 bf16 (4 VGPRs)
using facc  = __attribute__((ext_vector_type(4))) float;   // 4 fp32 acc

__device__ __forceinline__ float bf2f(ushort u) {
    return __uint_as_float(((unsigned)u) << 16);
}
__device__ __forceinline__ ushort f2bf(float f) {
    unsigned x = __float_as_uint(f);
    return (ushort)((x + 0x7FFFu + ((x >> 16) & 1u)) >> 16);   // RNE
}
__device__ __forceinline__ float4 bf4_f4(ushort4 u) {
    return make_float4(bf2f(u.x), bf2f(u.y), bf2f(u.z), bf2f(u.w));
}
__device__ __forceinline__ unsigned pack2(float a, float b) {
    return (unsigned)f2bf(a) | ((unsigned)f2bf(b) << 16);
}
__device__ __forceinline__ void gload16(const ushort* g, ushort* l) {
    __builtin_amdgcn_global_load_lds(
        (const __attribute__((address_space(1))) unsigned*)g,
        (__attribute__((address_space(3))) unsigned*)l, 16, 0, 0);
}

// ---------------------------------------------------------------------------
// fp32 -> bf16 convert (4 elems/thread)
// ---------------------------------------------------------------------------
__global__ __launch_bounds__(256)
void cvt_k(const float* __restrict__ s, ushort* __restrict__ d) {
    const size_t i = (size_t)(blockIdx.x * 256 + threadIdx.x) * 4;
    const float4 f = *(const float4*)(s + i);
    *(ushort4*)(d + i) = make_ushort4(f2bf(f.x), f2bf(f.y), f2bf(f.z), f2bf(f.w));
}

// ---------------------------------------------------------------------------
// Transpose-convert: W[R,C] fp32 -> WT[C,R] bf16. grid (C/64, R/64).
// ---------------------------------------------------------------------------
__global__ __launch_bounds__(256)
void tconv_k(const float* __restrict__ W, ushort* __restrict__ WT,
             const int R, const int C) {
    __shared__ ushort T[64][68];
    const int tid = threadIdx.x;
    const int c0 = blockIdx.x * 64, r0 = blockIdx.y * 64;
    #pragma unroll
    for (int rr = 0; rr < 4; ++rr) {
        const int r = (tid >> 4) + rr * 16;
        const int c4 = (tid & 15) * 4;
        const float4 f = *(const float4*)(W + (size_t)(r0 + r) * C + c0 + c4);
        T[c4+0][r] = f2bf(f.x); T[c4+1][r] = f2bf(f.y);
        T[c4+2][r] = f2bf(f.z); T[c4+3][r] = f2bf(f.w);
    }
    __syncthreads();
    #pragma unroll
    for (int rr = 0; rr < 4; ++rr) {
        const int c = (tid >> 4) + rr * 16;
        const int r4 = (tid & 15) * 4;
        *(ushort4*)(WT + (size_t)(c0 + c) * R + r0 + r4) =
            make_ushort4(T[c][r4+0], T[c][r4+1], T[c][r4+2], T[c][r4+3]);
    }
}

// ---------------------------------------------------------------------------
// bf16 MFMA GEMM, m97 structure: 128x128 tile, 4 waves (2x2 of 64x64), BK=64.
//   out[m,n] = ACT( sum_k A[m,k]*B[k,n] + bias[n] ),  B given as BT[n,k].
// OMODE 0: fp32 row-major (stride DM). 1: bf16 scatter [g,h,l,d].
// 2: bf16 row-major (stride DM). 3: bf16 transposed scatter [g,h,d,l]
// (in-LDS swizzled transpose + coalesced stores; requires ACT=0).
// ---------------------------------------------------------------------------
template<int ACT, int OMODE>
__global__ __launch_bounds__(256, 2)
void mfma_gemm(const ushort* __restrict__ A0, const ushort* __restrict__ A1,
               const float* __restrict__ A2f,
               const int KA1, const int KA2, const int Ktot,
               const int lda, const int ldaf,
               const ushort* __restrict__ BT, const int ldb,
               const float* __restrict__ bias,
               float* __restrict__ outf, ushort* __restrict__ outb)
{
    __shared__ ushort sh[16384];           // As = sh[0:8192), Bs = sh[8192:)
    ushort* const As = sh;
    ushort* const Bs = sh + 8192;
    const int tid  = threadIdx.x;
    const int w    = tid >> 6;
    const int lane = tid & 63;
    const int ln   = lane & 15, qd = lane >> 4;
    const int wm = (w & 1) * 64, wn = (w >> 1) * 64;
    const int m0 = blockIdx.y * 128, n0 = blockIdx.x * 128;

    const int arow = (lane >> 3);        // row-in-chunk 0..7
    const int kc8  = (lane & 7) * 8;     // k offset (8 bf16 = 16 B)

    facc acc[4][4];
    #pragma unroll
    for (int i = 0; i < 4; ++i)
        #pragma unroll
        for (int j = 0; j < 4; ++j)
            acc[i][j] = (facc){0.f, 0.f, 0.f, 0.f};

    for (int k0 = 0; k0 < Ktot; k0 += 64) {
        __syncthreads();
        #pragma unroll
        for (int t = 0; t < 4; ++t) {
            const int c = w * 4 + t;
            gload16(BT + (size_t)(n0 + c * 8 + arow) * ldb + k0 + kc8,
                    &Bs[c * 512]);
        }
        if (k0 < KA2) {
            const ushort* Ab; int ko;
            if (k0 < KA1) { Ab = A0; ko = k0; }
            else          { Ab = A1; ko = k0 - KA1; }
            #pragma unroll
            for (int t = 0; t < 4; ++t) {
                const int c = w * 4 + t;
                gload16(Ab + (size_t)(m0 + c * 8 + arow) * lda + ko + kc8,
                        &As[c * 512]);
            }
        } else {           // fp32 source: load + convert + ds_write
            const int ko = k0 - KA2;
            #pragma unroll
            for (int t = 0; t < 4; ++t) {
                const int c = w * 4 + t;
                const float* src = A2f + (size_t)(m0 + c * 8 + arow) * ldaf + ko + kc8;
                const float4 f0 = *(const float4*)src;
                const float4 f1 = *(const float4*)(src + 4);
                uint4 p;
                p.x = pack2(f0.x, f0.y); p.y = pack2(f0.z, f0.w);
                p.z = pack2(f1.x, f1.y); p.w = pack2(f1.z, f1.w);
                *(uint4*)&As[c * 512 + lane * 8] = p;
            }
        }
        __syncthreads();

        #pragma unroll
        for (int ks = 0; ks < 2; ++ks) {
            bfrag af[4], bfv[4];
            #pragma unroll
            for (int i = 0; i < 4; ++i)
                af[i] = *(const bfrag*)&As[(wm + i*16 + ln) * 64 + ks*32 + qd*8];
            #pragma unroll
            for (int j = 0; j < 4; ++j)
                bfv[j] = *(const bfrag*)&Bs[(wn + j*16 + ln) * 64 + ks*32 + qd*8];
            #pragma unroll
            for (int i = 0; i < 4; ++i)
                #pragma unroll
                for (int j = 0; j < 4; ++j)
                    acc[i][j] = __builtin_amdgcn_mfma_f32_16x16x32_bf16(
                        af[i], bfv[j], acc[i][j], 0, 0, 0);
        }
    }

    if (OMODE == 3) {
        // ---- transposed epilogue: LDS swizzled transpose, coalesced store ----
        __syncthreads();
        #pragma unroll
        for (int j = 0; j < 4; ++j) {
            const int n_l = wn + j * 16 + ln;
            const float bn = bias[n0 + n_l];
            #pragma unroll
            for (int i = 0; i < 4; ++i) {
                #pragma unroll
                for (int r = 0; r < 4; ++r) {
                    const int m_l = wm + i * 16 + qd * 4 + r;
                    const int c = (m_l >> 3) ^ (n_l & 7);
                    sh[n_l * 128 + c * 8 + (m_l & 7)] = f2bf(acc[i][j][r] + bn);
                }
            }
        }
        __syncthreads();
        const int n_l = tid >> 1, half = tid & 1;
        const int n = n0 + n_l;
        const int g = m0 >> 9, l0 = m0 & 511;
        ushort* dst = outb + (((size_t)(g * NH + (n >> 6))) * DH + (n & 63)) * SL + l0;
        #pragma unroll
        for (int u = 0; u < 8; ++u) {
            const int c = half * 8 + u;
            const int cs = c ^ (n_l & 7);
            *(uint4*)(dst + c * 8) = *(const uint4*)&sh[n_l * 128 + cs * 8];
        }
        return;
    }

    // ---- standard epilogue: C/D layout col=lane&15, row=qd*4+r ----
    #pragma unroll
    for (int j = 0; j < 4; ++j) {
        const int n = n0 + wn + j * 16 + ln;
        const float bn = bias[n];
        #pragma unroll
        for (int i = 0; i < 4; ++i) {
            const int mb = m0 + wm + i * 16 + qd * 4;
            #pragma unroll
            for (int r = 0; r < 4; ++r) {
                float v = acc[i][j][r] + bn;
                if (ACT == 1)      v = 1.f / (1.f + __expf(-v));
                else if (ACT == 2) v = v > 0.f ? v : 0.f;
                const int m = mb + r;
                if (OMODE == 0) {
                    outf[(size_t)m * DM + n] = v;
                } else if (OMODE == 1) {
                    const int g = m >> 9, l = m & 511;
                    outb[(((size_t)(g * NH + (n >> 6))) * SL + l) * DH + (n & 63)] = f2bf(v);
                } else {
                    outb[(size_t)m * DM + n] = f2bf(v);
                }
            }
        }
    }
}

// ---------------------------------------------------------------------------
// MFMA fuzzy attention. One (b,h,128-q-tile) per block, 4 waves (2x2).
// Q [g,h,l,d] / K [g,h,l,d] / VT [g,h,d,l], all bf16. Scores in [0,1] ->
// exp without max subtraction. E round-trips LDS (XOR-swizzled) to convert
// MFMA C-layout -> A-layout for PV. Row sums in registers, combined via LDS.
// LDS = 16K (K) + 16K (VT) + 32K (E) = 64 KB -> 2 blocks/CU.
// ---------------------------------------------------------------------------
__global__ __launch_bounds__(256, 2)
void attn2_k(const ushort* __restrict__ Qm, const ushort* __restrict__ Km,
             const ushort* __restrict__ VTm, ushort* __restrict__ AO,
             float* __restrict__ RS)
{
    __shared__ ushort Ks[128 * 64];
    __shared__ ushort VTs[64 * 128];
    __shared__ ushort Es[128 * 128];
    const int tid  = threadIdx.x;
    const int w    = tid >> 6;
    const int lane = tid & 63;
    const int ln   = lane & 15, qd = lane >> 4;
    const int wm  = (w & 1) * 64;          // q offset of this wave
    const int wns = (w >> 1) * 64;         // key offset (S stage)
    const int wnd = (w >> 1) * 32;         // d offset (PV stage)
    const int qt = blockIdx.x, h = blockIdx.y, b = blockIdx.z;
    const size_t ho = ((size_t)(b * NH + h)) * SL * DH;
    const ushort* Qg  = Qm  + ho + (size_t)qt * 128 * DH;
    const ushort* Kg  = Km  + ho;
    const ushort* VTg = VTm + ho;

    // Q fragments: register-resident for the whole kernel
    bfrag qf[4][2];
    #pragma unroll
    for (int i = 0; i < 4; ++i)
        #pragma unroll
        for (int ks = 0; ks < 2; ++ks)
            qf[i][ks] = *(const bfrag*)(Qg + (size_t)(wm + i*16 + ln) * DH + ks*32 + qd*8);

    facc oacc[4][2];
    #pragma unroll
    for (int i = 0; i < 4; ++i)
        #pragma unroll
        for (int j = 0; j < 2; ++j)
            oacc[i][j] = (facc){0.f, 0.f, 0.f, 0.f};
    float rp[4][4];
    #pragma unroll
    for (int i = 0; i < 4; ++i)
        #pragma unroll
        for (int r = 0; r < 4; ++r)
            rp[i][r] = 0.f;

    const int arow = lane >> 3, kc8 = (lane & 7) * 8;    // K staging (64-ush rows)
    const int vrow = lane >> 4, vc8 = (lane & 15) * 8;   // VT staging (128-ush rows)

    for (int kc = 0; kc < 4; ++kc) {
        __syncthreads();   // prior-iteration LDS reads complete
        #pragma unroll
        for (int t = 0; t < 4; ++t) {
            const int c = w * 4 + t;
            gload16(Kg + (size_t)(kc*128 + c*8 + arow) * DH + kc8, &Ks[c * 512]);
            gload16(VTg + (size_t)(c*4 + vrow) * SL + kc*128 + vc8, &VTs[c * 512]);
        }
        __syncthreads();

        // ---- S = Q K^T (128x128) ----
        facc sacc[4][4];
        #pragma unroll
        for (int i = 0; i < 4; ++i)
            #pragma unroll
            for (int j = 0; j < 4; ++j)
                sacc[i][j] = (facc){0.f, 0.f, 0.f, 0.f};
        #pragma unroll
        for (int ks = 0; ks < 2; ++ks) {
            bfrag kf[4];
            #pragma unroll
            for (int j = 0; j < 4; ++j)
                kf[j] = *(const bfrag*)&Ks[(wns + j*16 + ln) * 64 + ks*32 + qd*8];
            #pragma unroll
            for (int i = 0; i < 4; ++i)
                #pragma unroll
                for (int j = 0; j < 4; ++j)
                    sacc[i][j] = __builtin_amdgcn_mfma_f32_16x16x32_bf16(
                        qf[i][ks], kf[j], sacc[i][j], 0, 0, 0);
        }

        // ---- exp, row-sum (regs), E -> LDS (swizzled [q][key]) ----
        #pragma unroll
        for (int i = 0; i < 4; ++i) {
            #pragma unroll
            for (int r = 0; r < 4; ++r) {
                const int q = wm + i*16 + qd*4 + r;
                float p = 0.f;
                #pragma unroll
                for (int j = 0; j < 4; ++j) {
                    const float e = __expf(sacc[i][j][r] * 0.015625f);
                    const int key = wns + j*16 + ln;
                    const int c = (key >> 3) ^ (q & 7);
                    Es[q * 128 + c * 8 + (key & 7)] = f2bf(e);
                    p += e;
                }
                p += __shfl_xor(p, 1, 16);
                p += __shfl_xor(p, 2, 16);
                p += __shfl_xor(p, 4, 16);
                p += __shfl_xor(p, 8, 16);
                rp[i][r] += p;
            }
        }
        __syncthreads();

        // ---- O += E V (contract over 128 keys) ----
        #pragma unroll
        for (int ks2 = 0; ks2 < 4; ++ks2) {
            bfrag ea[4], vb[2];
            #pragma unroll
            for (int i = 0; i < 4; ++i) {
                const int q = wm + i*16 + ln;
                const int cs = (ks2*4 + qd) ^ (q & 7);
                ea[i] = *(const bfrag*)&Es[q * 128 + cs * 8];
            }
            #pragma unroll
            for (int j = 0; j < 2; ++j)
                vb[j] = *(const bfrag*)&VTs[(wnd + j*16 + ln) * 128 + ks2*32 + qd*8];
            #pragma unroll
            for (int i = 0; i < 4; ++i)
                #pragma unroll
                for (int j = 0; j < 2; ++j)
                    oacc[i][j] = __builtin_amdgcn_mfma_f32_16x16x32_bf16(
                        ea[i], vb[j], oacc[i][j], 0, 0, 0);
        }
    }

    // ---- combine row-sums across the two co-owning waves (reuse Ks) ----
    __syncthreads();
    float* rsls = (float*)Ks;
    if (ln == 0) {
        #pragma unroll
        for (int i = 0; i < 4; ++i)
            #pragma unroll
            for (int r = 0; r < 4; ++r)
                rsls[(w >> 1) * 128 + wm + i*16 + qd*4 + r] = rp[i][r];
    }
    __syncthreads();
    if (tid < 128) {
        const float t = rsls[tid] + rsls[128 + tid];
        RS[(size_t)(b * NH + h) * SL + qt * 128 + tid] = t;
        rsls[tid] = t;
    }
    __syncthreads();

    // ---- epilogue: normalize, store AO row-major [l][h*DH+d] bf16 ----
    #pragma unroll
    for (int i = 0; i < 4; ++i) {
        #pragma unroll
        for (int r = 0; r < 4; ++r) {
            const int q = wm + i*16 + qd*4 + r;
            const float inv = 1.f / rsls[q];
            const size_t rowo = ((size_t)(b*SL + qt*128 + q)) * DM + h*DH;
            #pragma unroll
            for (int j = 0; j < 2; ++j)
                AO[rowo + wnd + j*16 + ln] = f2bf(oacc[i][j][r] * inv);
        }
    }
}

// ---------------------------------------------------------------------------
// avg_attn: mean over heads of softmax rows, recomputed from bf16 Q/K with
// precomputed row sums (RS). One 64x64 output tile per block, 16-head loop.
// ---------------------------------------------------------------------------
__global__ __launch_bounds__(256)
void avg2_k(const ushort* __restrict__ Qm, const ushort* __restrict__ Km,
            const float* __restrict__ RS, float* __restrict__ avga)
{
    __shared__ float Qs[64][68];
    __shared__ float Kc[64][68];
    __shared__ float rss[64];
    const int tid = threadIdx.x;
    const int ty = tid >> 4, tx = tid & 15;
    const int kt = blockIdx.x, qt = blockIdx.y, b = blockIdx.z;

    float acc[4][4] = {};
    for (int h = 0; h < NH; ++h) {
        const size_t headoff = ((size_t)(b*NH + h)) * SL * DH;
        __syncthreads();
        #pragma unroll
        for (int r = 0; r < 4; ++r) {
            const int f = tid + 256*r;
            const int row = f >> 4, d4 = (f & 15) * 4;
            *(float4*)&Qs[row][d4] =
                bf4_f4(*(const ushort4*)(Qm + headoff + (size_t)(qt*64 + row)*DH + d4));
            *(float4*)&Kc[row][d4] =
                bf4_f4(*(const ushort4*)(Km + headoff + (size_t)(kt*64 + row)*DH + d4));
        }
        if (tid < 64) rss[tid] = RS[(size_t)(b*NH + h)*SL + qt*64 + tid];
        __syncthreads();

        float s[4][4] = {};
        #pragma unroll
        for (int d4 = 0; d4 < 16; ++d4) {
            float4 qv[4], kv[4];
            #pragma unroll
            for (int i = 0; i < 4; ++i) qv[i] = *(const float4*)&Qs[ty+16*i][4*d4];
            #pragma unroll
            for (int j = 0; j < 4; ++j) kv[j] = *(const float4*)&Kc[tx+16*j][4*d4];
            #pragma unroll
            for (int i = 0; i < 4; ++i)
                #pragma unroll
                for (int j = 0; j < 4; ++j)
                    s[i][j] += qv[i].x*kv[j].x + qv[i].y*kv[j].y
                             + qv[i].z*kv[j].z + qv[i].w*kv[j].w;
        }
        #pragma unroll
        for (int i = 0; i < 4; ++i) {
            const float ir = 0.0625f / rss[ty+16*i];
            #pragma unroll
            for (int j = 0; j < 4; ++j)
                acc[i][j] += __expf(s[i][j] * 0.015625f) * ir;
        }
    }
    #pragma unroll
    for (int i = 0; i < 4; ++i)
        #pragma unroll
        for (int j = 0; j < 4; ++j)
            avga[((size_t)(b*SL + qt*64 + ty+16*i))*SL + kt*64 + tx+16*j] = acc[i][j];
}

// ---------------------------------------------------------------------------
extern "C" void kernel_launch(void* const* d_in, const int* in_sizes, int n_in,
                              void* d_out, int out_size, void* d_ws, size_t ws_size,
                              hipStream_t stream)
{
    (void)in_sizes; (void)n_in; (void)out_size; (void)ws_size;
    const float* text  = (const float*)d_in[0];
    const float* image = (const float*)d_in[1];
    const float* Wq = (const float*)d_in[2];
    const float* bq = (const float*)d_in[3];
    const float* Wk = (const float*)d_in[4];
    const float* bk = (const float*)d_in[5];
    const float* Wv = (const float*)d_in[6];
    const float* bv = (const float*)d_in[7];
    const float* Wo = (const float*)d_in[8];
    const float* bo = (const float*)d_in[9];
    const float* W1 = (const float*)d_in[10];
    const float* b1 = (const float*)d_in[11];
    const float* W2 = (const float*)d_in[12];
    const float* b2 = (const float*)d_in[13];
    float* out = (float*)d_out;

    const size_t SZ   = (size_t)NB * SL * DM;   // 4,194,304
    const size_t HALF = SZ;                     // one direction of [16,NH,SL,DH]

    // ---- workspace layout (bf16 = ushort), ~82.1 MB ----
    ushort* xbf = (ushort*)d_ws;        // [8192,1024] text 0..4095, image 4096..
    ushort* Qb  = xbf + 2*SZ;           // [16,NH,SL,DH]
    ushort* Kb  = Qb  + 2*SZ;           // [16,NH,SL,DH]
    ushort* VT  = Kb  + 2*SZ;           // [16,NH,DH,SL]  (transposed V)
    ushort* AOt = VT  + 2*SZ;           // [4096,1024]
    ushort* Wt  = AOt + SZ;             // transposed-weight scratch
    float*  RS  = (float*)(Wt + 3*DM*DM);   // [8,NH,SL]
    ushort* AOi    = VT + HALF;         // reuses VT-image (dead after attn dir-1)
    ushort* hidden = Qb;                // reuses Q-text (dead after avg2)

    float* text_cross  = out;
    float* image_cross = out + SZ;
    float* comp        = out + 2*SZ;
    float* avga        = out + 3*SZ;

    const dim3 blk(256);
    const dim3 gQKV(8, 64);     // N=1024, M=8192
    const dim3 gHALFM(8, 32);   // N=1024, M=4096
    const dim3 ag(SL/128, NH, NB);

    // ---- convert activations to bf16 ----
    cvt_k<<<4096, blk, 0, stream>>>(text,  xbf);
    cvt_k<<<4096, blk, 0, stream>>>(image, xbf + SZ);

    // ---- Q/K/V projections (text+image batched along M) ----
    tconv_k<<<dim3(16,16), blk, 0, stream>>>(Wq, Wt,           DM, DM);
    tconv_k<<<dim3(16,16), blk, 0, stream>>>(Wk, Wt + DM*DM,   DM, DM);
    tconv_k<<<dim3(16,16), blk, 0, stream>>>(Wv, Wt + 2*DM*DM, DM, DM);
    mfma_gemm<1,1><<<gQKV, blk, 0, stream>>>(xbf, xbf, nullptr, DM, DM, DM, DM, DM,
                                             Wt,           DM, bq, nullptr, Qb);
    mfma_gemm<1,1><<<gQKV, blk, 0, stream>>>(xbf, xbf, nullptr, DM, DM, DM, DM, DM,
                                             Wt + DM*DM,   DM, bk, nullptr, Kb);
    mfma_gemm<0,3><<<gQKV, blk, 0, stream>>>(xbf, xbf, nullptr, DM, DM, DM, DM, DM,
                                             Wt + 2*DM*DM, DM, bv, nullptr, VT);

    // ---- attention dir-1 (Q text, K/V image), avg_attn, dir-2 ----
    attn2_k<<<ag, blk, 0, stream>>>(Qb, Kb + HALF, VT + HALF, AOt, RS);
    avg2_k<<<dim3(SL/64, SL/64, NB), blk, 0, stream>>>(Qb, Kb + HALF, RS, avga);
    attn2_k<<<ag, blk, 0, stream>>>(Qb + HALF, Kb, VT, AOi, RS);

    // ---- output projections ----
    tconv_k<<<dim3(16,16), blk, 0, stream>>>(Wo, Wt, DM, DM);
    mfma_gemm<0,0><<<gHALFM, blk, 0, stream>>>(AOt, AOt, nullptr, DM, DM, DM, DM, DM,
                                               Wt, DM, bo, text_cross, nullptr);
    mfma_gemm<0,0><<<gHALFM, blk, 0, stream>>>(AOi, AOi, nullptr, DM, DM, DM, DM, DM,
                                               Wt, DM, bo, image_cross, nullptr);

    // ---- MLP: concat(text, image, text_cross) @ W1 -> relu -> @ W2 ----
    tconv_k<<<dim3(16,48), blk, 0, stream>>>(W1, Wt, 3*DM, DM);
    mfma_gemm<2,2><<<gHALFM, blk, 0, stream>>>(xbf, xbf + SZ, text_cross,
                                               DM, 2*DM, 3*DM, DM, DM,
                                               Wt, 3*DM, b1, nullptr, hidden);
    tconv_k<<<dim3(16,16), blk, 0, stream>>>(W2, Wt, DM, DM);
    mfma_gemm<0,0><<<gHALFM, blk, 0, stream>>>(hidden, hidden, nullptr, DM, DM, DM, DM, DM,
                                               Wt, DM, b2, comp, nullptr);
}

// Round 5
// 503.361 us; speedup vs baseline: 5.2750x; 1.1343x over previous
//
#include <hip/hip_runtime.h>

#define NB 8
#define SL 512
#define DM 1024
#define NH 16
#define DH 64

using bfrag = __attribute__((ext_vector_type(8))) short;   // 8 bf16 (4 VGPRs)
using facc  = __attribute__((ext_vector_type(4))) float;   // 4 fp32 acc

__device__ __forceinline__ float bf2f(ushort u) {
    return __uint_as_float(((unsigned)u) << 16);
}
__device__ __forceinline__ ushort f2bf(float f) {
    unsigned x = __float_as_uint(f);
    return (ushort)((x + 0x7FFFu + ((x >> 16) & 1u)) >> 16);   // RNE
}
__device__ __forceinline__ float4 bf4_f4(ushort4 u) {
    return make_float4(bf2f(u.x), bf2f(u.y), bf2f(u.z), bf2f(u.w));
}
__device__ __forceinline__ unsigned pack2(float a, float b) {
    return (unsigned)f2bf(a) | ((unsigned)f2bf(b) << 16);
}
__device__ __forceinline__ void gload16(const ushort* g, ushort* l) {
    __builtin_amdgcn_global_load_lds(
        (const __attribute__((address_space(1))) unsigned*)g,
        (__attribute__((address_space(3))) unsigned*)l, 16, 0, 0);
}

// ---------------------------------------------------------------------------
// fp32 -> bf16 convert (4 elems/thread)
// ---------------------------------------------------------------------------
__global__ __launch_bounds__(256)
void cvt_k(const float* __restrict__ s, ushort* __restrict__ d) {
    const size_t i = (size_t)(blockIdx.x * 256 + threadIdx.x) * 4;
    const float4 f = *(const float4*)(s + i);
    *(ushort4*)(d + i) = make_ushort4(f2bf(f.x), f2bf(f.y), f2bf(f.z), f2bf(f.w));
}

// ---------------------------------------------------------------------------
// Transpose-convert: W[R,C] fp32 -> WT[C,R] bf16. grid (C/64, R/64).
// ---------------------------------------------------------------------------
__global__ __launch_bounds__(256)
void tconv_k(const float* __restrict__ W, ushort* __restrict__ WT,
             const int R, const int C) {
    __shared__ ushort T[64][68];
    const int tid = threadIdx.x;
    const int c0 = blockIdx.x * 64, r0 = blockIdx.y * 64;
    #pragma unroll
    for (int rr = 0; rr < 4; ++rr) {
        const int r = (tid >> 4) + rr * 16;
        const int c4 = (tid & 15) * 4;
        const float4 f = *(const float4*)(W + (size_t)(r0 + r) * C + c0 + c4);
        T[c4+0][r] = f2bf(f.x); T[c4+1][r] = f2bf(f.y);
        T[c4+2][r] = f2bf(f.z); T[c4+3][r] = f2bf(f.w);
    }
    __syncthreads();
    #pragma unroll
    for (int rr = 0; rr < 4; ++rr) {
        const int c = (tid >> 4) + rr * 16;
        const int r4 = (tid & 15) * 4;
        *(ushort4*)(WT + (size_t)(c0 + c) * R + r0 + r4) =
            make_ushort4(T[c][r4+0], T[c][r4+1], T[c][r4+2], T[c][r4+3]);
    }
}

// ---------------------------------------------------------------------------
// bf16 MFMA GEMM, m97 structure: 128x128 tile, 4 waves (2x2 of 64x64), BK=64.
//   out[m,n] = ACT( sum_k A[m,k]*B[k,n] + bias[n] ),  B given as BT[n,k].
// OMODE 0: fp32 row-major (stride DM). 1: bf16 scatter [g,h,l,d].
// 2: bf16 row-major (stride DM). 3: bf16 transposed scatter [g,h,d,l]
// (in-LDS swizzled transpose + coalesced stores; requires ACT=0).
// ---------------------------------------------------------------------------
template<int ACT, int OMODE>
__global__ __launch_bounds__(256, 2)
void mfma_gemm(const ushort* __restrict__ A0, const ushort* __restrict__ A1,
               const float* __restrict__ A2f,
               const int KA1, const int KA2, const int Ktot,
               const int lda, const int ldaf,
               const ushort* __restrict__ BT, const int ldb,
               const float* __restrict__ bias,
               float* __restrict__ outf, ushort* __restrict__ outb)
{
    __shared__ ushort sh[16384];           // As = sh[0:8192), Bs = sh[8192:)
    ushort* const As = sh;
    ushort* const Bs = sh + 8192;
    const int tid  = threadIdx.x;
    const int w    = tid >> 6;
    const int lane = tid & 63;
    const int ln   = lane & 15, qd = lane >> 4;
    const int wm = (w & 1) * 64, wn = (w >> 1) * 64;
    const int m0 = blockIdx.y * 128, n0 = blockIdx.x * 128;

    const int arow = (lane >> 3);        // row-in-chunk 0..7
    const int kc8  = (lane & 7) * 8;     // k offset (8 bf16 = 16 B)

    facc acc[4][4];
    #pragma unroll
    for (int i = 0; i < 4; ++i)
        #pragma unroll
        for (int j = 0; j < 4; ++j)
            acc[i][j] = (facc){0.f, 0.f, 0.f, 0.f};

    for (int k0 = 0; k0 < Ktot; k0 += 64) {
        __syncthreads();
        #pragma unroll
        for (int t = 0; t < 4; ++t) {
            const int c = w * 4 + t;
            gload16(BT + (size_t)(n0 + c * 8 + arow) * ldb + k0 + kc8,
                    &Bs[c * 512]);
        }
        if (k0 < KA2) {
            const ushort* Ab; int ko;
            if (k0 < KA1) { Ab = A0; ko = k0; }
            else          { Ab = A1; ko = k0 - KA1; }
            #pragma unroll
            for (int t = 0; t < 4; ++t) {
                const int c = w * 4 + t;
                gload16(Ab + (size_t)(m0 + c * 8 + arow) * lda + ko + kc8,
                        &As[c * 512]);
            }
        } else {           // fp32 source: load + convert + ds_write
            const int ko = k0 - KA2;
            #pragma unroll
            for (int t = 0; t < 4; ++t) {
                const int c = w * 4 + t;
                const float* src = A2f + (size_t)(m0 + c * 8 + arow) * ldaf + ko + kc8;
                const float4 f0 = *(const float4*)src;
                const float4 f1 = *(const float4*)(src + 4);
                uint4 p;
                p.x = pack2(f0.x, f0.y); p.y = pack2(f0.z, f0.w);
                p.z = pack2(f1.x, f1.y); p.w = pack2(f1.z, f1.w);
                *(uint4*)&As[c * 512 + lane * 8] = p;
            }
        }
        __syncthreads();

        #pragma unroll
        for (int ks = 0; ks < 2; ++ks) {
            bfrag af[4], bfv[4];
            #pragma unroll
            for (int i = 0; i < 4; ++i)
                af[i] = *(const bfrag*)&As[(wm + i*16 + ln) * 64 + ks*32 + qd*8];
            #pragma unroll
            for (int j = 0; j < 4; ++j)
                bfv[j] = *(const bfrag*)&Bs[(wn + j*16 + ln) * 64 + ks*32 + qd*8];
            #pragma unroll
            for (int i = 0; i < 4; ++i)
                #pragma unroll
                for (int j = 0; j < 4; ++j)
                    acc[i][j] = __builtin_amdgcn_mfma_f32_16x16x32_bf16(
                        af[i], bfv[j], acc[i][j], 0, 0, 0);
        }
    }

    if (OMODE == 3) {
        // ---- transposed epilogue: LDS swizzled transpose, coalesced store ----
        __syncthreads();
        #pragma unroll
        for (int j = 0; j < 4; ++j) {
            const int n_l = wn + j * 16 + ln;
            const float bn = bias[n0 + n_l];
            #pragma unroll
            for (int i = 0; i < 4; ++i) {
                #pragma unroll
                for (int r = 0; r < 4; ++r) {
                    const int m_l = wm + i * 16 + qd * 4 + r;
                    const int c = (m_l >> 3) ^ (n_l & 7);
                    sh[n_l * 128 + c * 8 + (m_l & 7)] = f2bf(acc[i][j][r] + bn);
                }
            }
        }
        __syncthreads();
        const int n_l = tid >> 1, half = tid & 1;
        const int n = n0 + n_l;
        const int g = m0 >> 9, l0 = m0 & 511;
        ushort* dst = outb + (((size_t)(g * NH + (n >> 6))) * DH + (n & 63)) * SL + l0;
        #pragma unroll
        for (int u = 0; u < 8; ++u) {
            const int c = half * 8 + u;
            const int cs = c ^ (n_l & 7);
            *(uint4*)(dst + c * 8) = *(const uint4*)&sh[n_l * 128 + cs * 8];
        }
        return;
    }

    // ---- standard epilogue: C/D layout col=lane&15, row=qd*4+r ----
    #pragma unroll
    for (int j = 0; j < 4; ++j) {
        const int n = n0 + wn + j * 16 + ln;
        const float bn = bias[n];
        #pragma unroll
        for (int i = 0; i < 4; ++i) {
            const int mb = m0 + wm + i * 16 + qd * 4;
            #pragma unroll
            for (int r = 0; r < 4; ++r) {
                float v = acc[i][j][r] + bn;
                if (ACT == 1)      v = 1.f / (1.f + __expf(-v));
                else if (ACT == 2) v = v > 0.f ? v : 0.f;
                const int m = mb + r;
                if (OMODE == 0) {
                    outf[(size_t)m * DM + n] = v;
                } else if (OMODE == 1) {
                    const int g = m >> 9, l = m & 511;
                    outb[(((size_t)(g * NH + (n >> 6))) * SL + l) * DH + (n & 63)] = f2bf(v);
                } else {
                    outb[(size_t)m * DM + n] = f2bf(v);
                }
            }
        }
    }
}

// ---------------------------------------------------------------------------
// MFMA fuzzy attention. One (b,h,128-q-tile) per block, 4 waves (2x2).
// Q [g,h,l,d] / K [g,h,l,d] / VT [g,h,d,l], all bf16. Scores in [0,1] ->
// exp without max subtraction. E round-trips LDS (XOR-swizzled) to convert
// MFMA C-layout -> A-layout for PV. Row sums in registers, combined via LDS.
// LDS = 16K (K) + 16K (VT) + 32K (E) = 64 KB -> 2 blocks/CU.
// ---------------------------------------------------------------------------
__global__ __launch_bounds__(256, 2)
void attn2_k(const ushort* __restrict__ Qm, const ushort* __restrict__ Km,
             const ushort* __restrict__ VTm, ushort* __restrict__ AO,
             float* __restrict__ RS)
{
    __shared__ ushort Ks[128 * 64];
    __shared__ ushort VTs[64 * 128];
    __shared__ ushort Es[128 * 128];
    const int tid  = threadIdx.x;
    const int w    = tid >> 6;
    const int lane = tid & 63;
    const int ln   = lane & 15, qd = lane >> 4;
    const int wm  = (w & 1) * 64;          // q offset of this wave
    const int wns = (w >> 1) * 64;         // key offset (S stage)
    const int wnd = (w >> 1) * 32;         // d offset (PV stage)
    const int qt = blockIdx.x, h = blockIdx.y, b = blockIdx.z;
    const size_t ho = ((size_t)(b * NH + h)) * SL * DH;
    const ushort* Qg  = Qm  + ho + (size_t)qt * 128 * DH;
    const ushort* Kg  = Km  + ho;
    const ushort* VTg = VTm + ho;

    // Q fragments: register-resident for the whole kernel
    bfrag qf[4][2];
    #pragma unroll
    for (int i = 0; i < 4; ++i)
        #pragma unroll
        for (int ks = 0; ks < 2; ++ks)
            qf[i][ks] = *(const bfrag*)(Qg + (size_t)(wm + i*16 + ln) * DH + ks*32 + qd*8);

    facc oacc[4][2];
    #pragma unroll
    for (int i = 0; i < 4; ++i)
        #pragma unroll
        for (int j = 0; j < 2; ++j)
            oacc[i][j] = (facc){0.f, 0.f, 0.f, 0.f};
    float rp[4][4];
    #pragma unroll
    for (int i = 0; i < 4; ++i)
        #pragma unroll
        for (int r = 0; r < 4; ++r)
            rp[i][r] = 0.f;

    const int arow = lane >> 3, kc8 = (lane & 7) * 8;    // K staging (64-ush rows)
    const int vrow = lane >> 4, vc8 = (lane & 15) * 8;   // VT staging (128-ush rows)

    for (int kc = 0; kc < 4; ++kc) {
        __syncthreads();   // prior-iteration LDS reads complete
        #pragma unroll
        for (int t = 0; t < 4; ++t) {
            const int c = w * 4 + t;
            gload16(Kg + (size_t)(kc*128 + c*8 + arow) * DH + kc8, &Ks[c * 512]);
            gload16(VTg + (size_t)(c*4 + vrow) * SL + kc*128 + vc8, &VTs[c * 512]);
        }
        __syncthreads();

        // ---- S = Q K^T (128x128) ----
        facc sacc[4][4];
        #pragma unroll
        for (int i = 0; i < 4; ++i)
            #pragma unroll
            for (int j = 0; j < 4; ++j)
                sacc[i][j] = (facc){0.f, 0.f, 0.f, 0.f};
        #pragma unroll
        for (int ks = 0; ks < 2; ++ks) {
            bfrag kf[4];
            #pragma unroll
            for (int j = 0; j < 4; ++j)
                kf[j] = *(const bfrag*)&Ks[(wns + j*16 + ln) * 64 + ks*32 + qd*8];
            #pragma unroll
            for (int i = 0; i < 4; ++i)
                #pragma unroll
                for (int j = 0; j < 4; ++j)
                    sacc[i][j] = __builtin_amdgcn_mfma_f32_16x16x32_bf16(
                        qf[i][ks], kf[j], sacc[i][j], 0, 0, 0);
        }

        // ---- exp, row-sum (regs), E -> LDS (swizzled [q][key]) ----
        #pragma unroll
        for (int i = 0; i < 4; ++i) {
            #pragma unroll
            for (int r = 0; r < 4; ++r) {
                const int q = wm + i*16 + qd*4 + r;
                float p = 0.f;
                #pragma unroll
                for (int j = 0; j < 4; ++j) {
                    const float e = __expf(sacc[i][j][r] * 0.015625f);
                    const int key = wns + j*16 + ln;
                    const int c = (key >> 3) ^ (q & 7);
                    Es[q * 128 + c * 8 + (key & 7)] = f2bf(e);
                    p += e;
                }
                p += __shfl_xor(p, 1, 16);
                p += __shfl_xor(p, 2, 16);
                p += __shfl_xor(p, 4, 16);
                p += __shfl_xor(p, 8, 16);
                rp[i][r] += p;
            }
        }
        __syncthreads();

        // ---- O += E V (contract over 128 keys) ----
        #pragma unroll
        for (int ks2 = 0; ks2 < 4; ++ks2) {
            bfrag ea[4], vb[2];
            #pragma unroll
            for (int i = 0; i < 4; ++i) {
                const int q = wm + i*16 + ln;
                const int cs = (ks2*4 + qd) ^ (q & 7);
                ea[i] = *(const bfrag*)&Es[q * 128 + cs * 8];
            }
            #pragma unroll
            for (int j = 0; j < 2; ++j)
                vb[j] = *(const bfrag*)&VTs[(wnd + j*16 + ln) * 128 + ks2*32 + qd*8];
            #pragma unroll
            for (int i = 0; i < 4; ++i)
                #pragma unroll
                for (int j = 0; j < 2; ++j)
                    oacc[i][j] = __builtin_amdgcn_mfma_f32_16x16x32_bf16(
                        ea[i], vb[j], oacc[i][j], 0, 0, 0);
        }
    }

    // ---- combine row-sums across the two co-owning waves (reuse Ks) ----
    __syncthreads();
    float* rsls = (float*)Ks;
    if (ln == 0) {
        #pragma unroll
        for (int i = 0; i < 4; ++i)
            #pragma unroll
            for (int r = 0; r < 4; ++r)
                rsls[(w >> 1) * 128 + wm + i*16 + qd*4 + r] = rp[i][r];
    }
    __syncthreads();
    if (tid < 128) {
        const float t = rsls[tid] + rsls[128 + tid];
        RS[(size_t)(b * NH + h) * SL + qt * 128 + tid] = t;
        rsls[tid] = t;
    }
    __syncthreads();

    // ---- epilogue: normalize, store AO row-major [l][h*DH+d] bf16 ----
    #pragma unroll
    for (int i = 0; i < 4; ++i) {
        #pragma unroll
        for (int r = 0; r < 4; ++r) {
            const int q = wm + i*16 + qd*4 + r;
            const float inv = 1.f / rsls[q];
            const size_t rowo = ((size_t)(b*SL + qt*128 + q)) * DM + h*DH;
            #pragma unroll
            for (int j = 0; j < 2; ++j)
                AO[rowo + wnd + j*16 + ln] = f2bf(oacc[i][j][r] * inv);
        }
    }
}

// ---------------------------------------------------------------------------
// avg_attn via MFMA: one 64x64 avga tile per block (grid 8x8x8), 16-head
// loop. Q/K staged raw bf16 via global_load_lds; scores on the matrix pipe
// (2x2 16x16x32 frags/wave x 2 k-steps); exp + head-accumulate on VALU.
// Replaces the scalar-FMA avg2_k (99 us, VALU-bound at 80%).
// ---------------------------------------------------------------------------
__global__ __launch_bounds__(256, 2)
void avg3_k(const ushort* __restrict__ Qm, const ushort* __restrict__ Km,
            const float* __restrict__ RS, float* __restrict__ avga)
{
    __shared__ ushort Qs[64 * 64];
    __shared__ ushort Kt[64 * 64];
    __shared__ float rss[64];
    const int tid  = threadIdx.x;
    const int w    = tid >> 6;
    const int lane = tid & 63;
    const int ln   = lane & 15, qd = lane >> 4;
    const int wq = (w & 1) * 32, wk = (w >> 1) * 32;
    const int kt = blockIdx.x, qt = blockIdx.y, b = blockIdx.z;

    const int arow = lane >> 3, kc8 = (lane & 7) * 8;

    float acc[2][2][4];
    #pragma unroll
    for (int i = 0; i < 2; ++i)
        #pragma unroll
        for (int j = 0; j < 2; ++j)
            #pragma unroll
            for (int r = 0; r < 4; ++r)
                acc[i][j][r] = 0.f;

    for (int h = 0; h < NH; ++h) {
        const size_t ho = ((size_t)(b * NH + h)) * SL * DH;
        __syncthreads();   // prior head's frag reads complete
        #pragma unroll
        for (int t = 0; t < 2; ++t) {
            const int c = w * 2 + t;   // 8-row chunk
            gload16(Qm + ho + (size_t)(qt*64 + c*8 + arow) * DH + kc8, &Qs[c * 512]);
            gload16(Km + ho + (size_t)(kt*64 + c*8 + arow) * DH + kc8, &Kt[c * 512]);
        }
        if (tid < 64) rss[tid] = RS[(size_t)(b*NH + h)*SL + qt*64 + tid];
        __syncthreads();

        facc s[2][2];
        #pragma unroll
        for (int i = 0; i < 2; ++i)
            #pragma unroll
            for (int j = 0; j < 2; ++j)
                s[i][j] = (facc){0.f, 0.f, 0.f, 0.f};
        #pragma unroll
        for (int ks = 0; ks < 2; ++ks) {
            bfrag qa[2], kb[2];
            #pragma unroll
            for (int i = 0; i < 2; ++i)
                qa[i] = *(const bfrag*)&Qs[(wq + i*16 + ln) * 64 + ks*32 + qd*8];
            #pragma unroll
            for (int j = 0; j < 2; ++j)
                kb[j] = *(const bfrag*)&Kt[(wk + j*16 + ln) * 64 + ks*32 + qd*8];
            #pragma unroll
            for (int i = 0; i < 2; ++i)
                #pragma unroll
                for (int j = 0; j < 2; ++j)
                    s[i][j] = __builtin_amdgcn_mfma_f32_16x16x32_bf16(
                        qa[i], kb[j], s[i][j], 0, 0, 0);
        }
        // C/D layout: row(q) = qd*4+r, col(key) = ln
        #pragma unroll
        for (int i = 0; i < 2; ++i) {
            #pragma unroll
            for (int r = 0; r < 4; ++r) {
                const float ir = 0.0625f / rss[wq + i*16 + qd*4 + r];
                #pragma unroll
                for (int j = 0; j < 2; ++j)
                    acc[i][j][r] += __expf(s[i][j][r] * 0.015625f) * ir;
            }
        }
    }
    #pragma unroll
    for (int i = 0; i < 2; ++i) {
        #pragma unroll
        for (int r = 0; r < 4; ++r) {
            const int q = wq + i*16 + qd*4 + r;
            #pragma unroll
            for (int j = 0; j < 2; ++j)
                avga[((size_t)(b*SL + qt*64 + q)) * SL + kt*64 + wk + j*16 + ln]
                    = acc[i][j][r];
        }
    }
}

// ---------------------------------------------------------------------------
extern "C" void kernel_launch(void* const* d_in, const int* in_sizes, int n_in,
                              void* d_out, int out_size, void* d_ws, size_t ws_size,
                              hipStream_t stream)
{
    (void)in_sizes; (void)n_in; (void)out_size; (void)ws_size;
    const float* text  = (const float*)d_in[0];
    const float* image = (const float*)d_in[1];
    const float* Wq = (const float*)d_in[2];
    const float* bq = (const float*)d_in[3];
    const float* Wk = (const float*)d_in[4];
    const float* bk = (const float*)d_in[5];
    const float* Wv = (const float*)d_in[6];
    const float* bv = (const float*)d_in[7];
    const float* Wo = (const float*)d_in[8];
    const float* bo = (const float*)d_in[9];
    const float* W1 = (const float*)d_in[10];
    const float* b1 = (const float*)d_in[11];
    const float* W2 = (const float*)d_in[12];
    const float* b2 = (const float*)d_in[13];
    float* out = (float*)d_out;

    const size_t SZ   = (size_t)NB * SL * DM;   // 4,194,304
    const size_t HALF = SZ;                     // one direction of [16,NH,SL,DH]

    // ---- workspace layout (bf16 = ushort), ~82.1 MB ----
    ushort* xbf = (ushort*)d_ws;        // [8192,1024] text 0..4095, image 4096..
    ushort* Qb  = xbf + 2*SZ;           // [16,NH,SL,DH]
    ushort* Kb  = Qb  + 2*SZ;           // [16,NH,SL,DH]
    ushort* VT  = Kb  + 2*SZ;           // [16,NH,DH,SL]  (transposed V)
    ushort* AOt = VT  + 2*SZ;           // [4096,1024]
    ushort* Wt  = AOt + SZ;             // transposed-weight scratch
    float*  RS  = (float*)(Wt + 3*DM*DM);   // [8,NH,SL]
    ushort* AOi    = VT + HALF;         // reuses VT-image (dead after attn dir-1)
    ushort* hidden = Qb;                // reuses Q-text (dead after avg3)

    float* text_cross  = out;
    float* image_cross = out + SZ;
    float* comp        = out + 2*SZ;
    float* avga        = out + 3*SZ;

    const dim3 blk(256);
    const dim3 gQKV(8, 64);     // N=1024, M=8192
    const dim3 gHALFM(8, 32);   // N=1024, M=4096
    const dim3 ag(SL/128, NH, NB);

    // ---- convert activations to bf16 ----
    cvt_k<<<4096, blk, 0, stream>>>(text,  xbf);
    cvt_k<<<4096, blk, 0, stream>>>(image, xbf + SZ);

    // ---- Q/K/V projections (text+image batched along M) ----
    tconv_k<<<dim3(16,16), blk, 0, stream>>>(Wq, Wt,           DM, DM);
    tconv_k<<<dim3(16,16), blk, 0, stream>>>(Wk, Wt + DM*DM,   DM, DM);
    tconv_k<<<dim3(16,16), blk, 0, stream>>>(Wv, Wt + 2*DM*DM, DM, DM);
    mfma_gemm<1,1><<<gQKV, blk, 0, stream>>>(xbf, xbf, nullptr, DM, DM, DM, DM, DM,
                                             Wt,           DM, bq, nullptr, Qb);
    mfma_gemm<1,1><<<gQKV, blk, 0, stream>>>(xbf, xbf, nullptr, DM, DM, DM, DM, DM,
                                             Wt + DM*DM,   DM, bk, nullptr, Kb);
    mfma_gemm<0,3><<<gQKV, blk, 0, stream>>>(xbf, xbf, nullptr, DM, DM, DM, DM, DM,
                                             Wt + 2*DM*DM, DM, bv, nullptr, VT);

    // ---- attention dir-1 (Q text, K/V image), avg_attn, dir-2 ----
    attn2_k<<<ag, blk, 0, stream>>>(Qb, Kb + HALF, VT + HALF, AOt, RS);
    avg3_k<<<dim3(SL/64, SL/64, NB), blk, 0, stream>>>(Qb, Kb + HALF, RS, avga);
    attn2_k<<<ag, blk, 0, stream>>>(Qb + HALF, Kb, VT, AOi, RS);

    // ---- output projections ----
    tconv_k<<<dim3(16,16), blk, 0, stream>>>(Wo, Wt, DM, DM);
    mfma_gemm<0,0><<<gHALFM, blk, 0, stream>>>(AOt, AOt, nullptr, DM, DM, DM, DM, DM,
                                               Wt, DM, bo, text_cross, nullptr);
    mfma_gemm<0,0><<<gHALFM, blk, 0, stream>>>(AOi, AOi, nullptr, DM, DM, DM, DM, DM,
                                               Wt, DM, bo, image_cross, nullptr);

    // ---- MLP: concat(text, image, text_cross) @ W1 -> relu -> @ W2 ----
    tconv_k<<<dim3(16,48), blk, 0, stream>>>(W1, Wt, 3*DM, DM);
    mfma_gemm<2,2><<<gHALFM, blk, 0, stream>>>(xbf, xbf + SZ, text_cross,
                                               DM, 2*DM, 3*DM, DM, DM,
                                               Wt, 3*DM, b1, nullptr, hidden);
    tconv_k<<<dim3(16,16), blk, 0, stream>>>(W2, Wt, DM, DM);
    mfma_gemm<0,0><<<gHALFM, blk, 0, stream>>>(hidden, hidden, nullptr, DM, DM, DM, DM, DM,
                                               Wt, DM, b2, comp, nullptr);
}

// Round 6
// 453.424 us; speedup vs baseline: 5.8559x; 1.1101x over previous
//
#include <hip/hip_runtime.h>

#define NB 8
#define SL 512
#define DM 1024
#define NH 16
#define DH 64

using bfrag = __attribute__((ext_vector_type(8))) short;   // 8 bf16 (4 VGPRs)
using facc  = __attribute__((ext_vector_type(4))) float;   // 4 fp32 acc

__device__ __forceinline__ float bf2f(ushort u) {
    return __uint_as_float(((unsigned)u) << 16);
}
__device__ __forceinline__ ushort f2bf(float f) {
    unsigned x = __float_as_uint(f);
    return (ushort)((x + 0x7FFFu + ((x >> 16) & 1u)) >> 16);   // RNE
}
__device__ __forceinline__ float4 bf4_f4(ushort4 u) {
    return make_float4(bf2f(u.x), bf2f(u.y), bf2f(u.z), bf2f(u.w));
}
__device__ __forceinline__ unsigned pack2(float a, float b) {
    return (unsigned)f2bf(a) | ((unsigned)f2bf(b) << 16);
}
__device__ __forceinline__ void gload16(const ushort* g, ushort* l) {
    __builtin_amdgcn_global_load_lds(
        (const __attribute__((address_space(1))) unsigned*)g,
        (__attribute__((address_space(3))) unsigned*)l, 16, 0, 0);
}

// ---------------------------------------------------------------------------
// fp32 -> bf16 convert (4 elems/thread)
// ---------------------------------------------------------------------------
__global__ __launch_bounds__(256)
void cvt_k(const float* __restrict__ s, ushort* __restrict__ d) {
    const size_t i = (size_t)(blockIdx.x * 256 + threadIdx.x) * 4;
    const float4 f = *(const float4*)(s + i);
    *(ushort4*)(d + i) = make_ushort4(f2bf(f.x), f2bf(f.y), f2bf(f.z), f2bf(f.w));
}

// ---------------------------------------------------------------------------
// Transpose-convert: W[R,C] fp32 -> WT[C,R] bf16. grid (C/64, R/64).
// ---------------------------------------------------------------------------
__global__ __launch_bounds__(256)
void tconv_k(const float* __restrict__ W, ushort* __restrict__ WT,
             const int R, const int C) {
    __shared__ ushort T[64][68];
    const int tid = threadIdx.x;
    const int c0 = blockIdx.x * 64, r0 = blockIdx.y * 64;
    #pragma unroll
    for (int rr = 0; rr < 4; ++rr) {
        const int r = (tid >> 4) + rr * 16;
        const int c4 = (tid & 15) * 4;
        const float4 f = *(const float4*)(W + (size_t)(r0 + r) * C + c0 + c4);
        T[c4+0][r] = f2bf(f.x); T[c4+1][r] = f2bf(f.y);
        T[c4+2][r] = f2bf(f.z); T[c4+3][r] = f2bf(f.w);
    }
    __syncthreads();
    #pragma unroll
    for (int rr = 0; rr < 4; ++rr) {
        const int c = (tid >> 4) + rr * 16;
        const int r4 = (tid & 15) * 4;
        *(ushort4*)(WT + (size_t)(c0 + c) * R + r0 + r4) =
            make_ushort4(T[c][r4+0], T[c][r4+1], T[c][r4+2], T[c][r4+3]);
    }
}

// ---------------------------------------------------------------------------
// bf16 MFMA GEMM, m97 structure: 128x128 tile, 4 waves (2x2 of 64x64), BK=64.
//   out[m,n] = ACT( sum_k A[m,k]*B[k,n] + bias[n] ),  B given as BT[n,k].
// XCD-clustered grid swizzle: blocks with (linear%8)==x cover m-tiles
// [x*MT/8, (x+1)*MT/8) x all n-tiles, so each XCD's L2 holds one A-slice +
// full B (fits 4 MB) -> A fetched from HBM once instead of NT times.
// XOR chunk swizzle on LDS tiles: slot (row,kc) holds global chunk
// kc^(row&7); kills the stride-128B bank conflicts on frag ds_read_b128.
// OMODE 0: fp32 row-major (stride DM). 1: bf16 scatter [g,h,l,d].
// 2: bf16 row-major (stride DM). 3: bf16 transposed scatter [g,h,d,l].
// ---------------------------------------------------------------------------
template<int ACT, int OMODE>
__global__ __launch_bounds__(256, 2)
void mfma_gemm(const ushort* __restrict__ A0, const ushort* __restrict__ A1,
               const float* __restrict__ A2f,
               const int KA1, const int KA2, const int Ktot,
               const int lda, const int ldaf,
               const ushort* __restrict__ BT, const int ldb,
               const float* __restrict__ bias,
               float* __restrict__ outf, ushort* __restrict__ outb)
{
    __shared__ ushort sh[16384];           // As = sh[0:8192), Bs = sh[8192:)
    ushort* const As = sh;
    ushort* const Bs = sh + 8192;
    const int tid  = threadIdx.x;
    const int w    = tid >> 6;
    const int lane = tid & 63;
    const int ln   = lane & 15, qd = lane >> 4;
    const int wm = (w & 1) * 64, wn = (w >> 1) * 64;

    // ---- XCD-clustered block swizzle (MT must be divisible by 8) ----
    const int NTg = gridDim.x, MTg = gridDim.y;
    const int L   = blockIdx.x + NTg * blockIdx.y;
    const int xcd = L & 7, s = L >> 3;
    const int mt  = xcd * (MTg >> 3) + s / NTg;
    const int nt  = s - (s / NTg) * NTg;
    const int m0 = mt * 128, n0 = nt * 128;

    const int arow = (lane >> 3);               // row-in-chunk 0..7
    const int kc8s = ((lane & 7) ^ arow) * 8;   // swizzled global k-chunk

    facc acc[4][4];
    #pragma unroll
    for (int i = 0; i < 4; ++i)
        #pragma unroll
        for (int j = 0; j < 4; ++j)
            acc[i][j] = (facc){0.f, 0.f, 0.f, 0.f};

    for (int k0 = 0; k0 < Ktot; k0 += 64) {
        __syncthreads();
        #pragma unroll
        for (int t = 0; t < 4; ++t) {
            const int c = w * 4 + t;
            gload16(BT + (size_t)(n0 + c * 8 + arow) * ldb + k0 + kc8s,
                    &Bs[c * 512]);
        }
        if (k0 < KA2) {
            const ushort* Ab; int ko;
            if (k0 < KA1) { Ab = A0; ko = k0; }
            else          { Ab = A1; ko = k0 - KA1; }
            #pragma unroll
            for (int t = 0; t < 4; ++t) {
                const int c = w * 4 + t;
                gload16(Ab + (size_t)(m0 + c * 8 + arow) * lda + ko + kc8s,
                        &As[c * 512]);
            }
        } else {           // fp32 source: load + convert + ds_write
            const int ko = k0 - KA2;
            #pragma unroll
            for (int t = 0; t < 4; ++t) {
                const int c = w * 4 + t;
                const float* src = A2f + (size_t)(m0 + c * 8 + arow) * ldaf + ko + kc8s;
                const float4 f0 = *(const float4*)src;
                const float4 f1 = *(const float4*)(src + 4);
                uint4 p;
                p.x = pack2(f0.x, f0.y); p.y = pack2(f0.z, f0.w);
                p.z = pack2(f1.x, f1.y); p.w = pack2(f1.z, f1.w);
                *(uint4*)&As[c * 512 + lane * 8] = p;
            }
        }
        __syncthreads();

        #pragma unroll
        for (int ks = 0; ks < 2; ++ks) {
            const int ch = (ks * 4 + qd) ^ (ln & 7);   // swizzled chunk
            bfrag af[4], bfv[4];
            #pragma unroll
            for (int i = 0; i < 4; ++i)
                af[i] = *(const bfrag*)&As[(wm + i*16 + ln) * 64 + ch * 8];
            #pragma unroll
            for (int j = 0; j < 4; ++j)
                bfv[j] = *(const bfrag*)&Bs[(wn + j*16 + ln) * 64 + ch * 8];
            #pragma unroll
            for (int i = 0; i < 4; ++i)
                #pragma unroll
                for (int j = 0; j < 4; ++j)
                    acc[i][j] = __builtin_amdgcn_mfma_f32_16x16x32_bf16(
                        af[i], bfv[j], acc[i][j], 0, 0, 0);
        }
    }

    if (OMODE == 3) {
        // ---- transposed epilogue: LDS swizzled transpose, coalesced store ----
        __syncthreads();
        #pragma unroll
        for (int j = 0; j < 4; ++j) {
            const int n_l = wn + j * 16 + ln;
            const float bn = bias[n0 + n_l];
            #pragma unroll
            for (int i = 0; i < 4; ++i) {
                #pragma unroll
                for (int r = 0; r < 4; ++r) {
                    const int m_l = wm + i * 16 + qd * 4 + r;
                    const int c = (m_l >> 3) ^ (n_l & 7);
                    sh[n_l * 128 + c * 8 + (m_l & 7)] = f2bf(acc[i][j][r] + bn);
                }
            }
        }
        __syncthreads();
        const int n_l = tid >> 1, half = tid & 1;
        const int n = n0 + n_l;
        const int g = m0 >> 9, l0 = m0 & 511;
        ushort* dst = outb + (((size_t)(g * NH + (n >> 6))) * DH + (n & 63)) * SL + l0;
        #pragma unroll
        for (int u = 0; u < 8; ++u) {
            const int c = half * 8 + u;
            const int cs = c ^ (n_l & 7);
            *(uint4*)(dst + c * 8) = *(const uint4*)&sh[n_l * 128 + cs * 8];
        }
        return;
    }

    // ---- standard epilogue: C/D layout col=lane&15, row=qd*4+r ----
    #pragma unroll
    for (int j = 0; j < 4; ++j) {
        const int n = n0 + wn + j * 16 + ln;
        const float bn = bias[n];
        #pragma unroll
        for (int i = 0; i < 4; ++i) {
            const int mb = m0 + wm + i * 16 + qd * 4;
            #pragma unroll
            for (int r = 0; r < 4; ++r) {
                float v = acc[i][j][r] + bn;
                if (ACT == 1)      v = 1.f / (1.f + __expf(-v));
                else if (ACT == 2) v = v > 0.f ? v : 0.f;
                const int m = mb + r;
                if (OMODE == 0) {
                    outf[(size_t)m * DM + n] = v;
                } else if (OMODE == 1) {
                    const int g = m >> 9, l = m & 511;
                    outb[(((size_t)(g * NH + (n >> 6))) * SL + l) * DH + (n & 63)] = f2bf(v);
                } else {
                    outb[(size_t)m * DM + n] = f2bf(v);
                }
            }
        }
    }
}

// ---------------------------------------------------------------------------
// MFMA fuzzy attention. One (b,h,128-q-tile) per block, 4 waves (2x2).
// Q [g,h,l,d] / K [g,h,l,d] / VT [g,h,d,l], all bf16. Scores in [0,1] ->
// exp without max subtraction. E round-trips LDS (XOR-swizzled) to convert
// MFMA C-layout -> A-layout for PV. K/VT tiles use the same XOR chunk
// swizzle as mfma_gemm (bank-conflict-free frag reads).
// LDS = 16K (K) + 16K (VT) + 32K (E) = 64 KB -> 2 blocks/CU.
// ---------------------------------------------------------------------------
__global__ __launch_bounds__(256, 2)
void attn2_k(const ushort* __restrict__ Qm, const ushort* __restrict__ Km,
             const ushort* __restrict__ VTm, ushort* __restrict__ AO,
             float* __restrict__ RS)
{
    __shared__ ushort Ks[128 * 64];
    __shared__ ushort VTs[64 * 128];
    __shared__ ushort Es[128 * 128];
    const int tid  = threadIdx.x;
    const int w    = tid >> 6;
    const int lane = tid & 63;
    const int ln   = lane & 15, qd = lane >> 4;
    const int wm  = (w & 1) * 64;          // q offset of this wave
    const int wns = (w >> 1) * 64;         // key offset (S stage)
    const int wnd = (w >> 1) * 32;         // d offset (PV stage)
    const int qt = blockIdx.x, h = blockIdx.y, b = blockIdx.z;
    const size_t ho = ((size_t)(b * NH + h)) * SL * DH;
    const ushort* Qg  = Qm  + ho + (size_t)qt * 128 * DH;
    const ushort* Kg  = Km  + ho;
    const ushort* VTg = VTm + ho;

    // Q fragments: register-resident for the whole kernel
    bfrag qf[4][2];
    #pragma unroll
    for (int i = 0; i < 4; ++i)
        #pragma unroll
        for (int ks = 0; ks < 2; ++ks)
            qf[i][ks] = *(const bfrag*)(Qg + (size_t)(wm + i*16 + ln) * DH + ks*32 + qd*8);

    facc oacc[4][2];
    #pragma unroll
    for (int i = 0; i < 4; ++i)
        #pragma unroll
        for (int j = 0; j < 2; ++j)
            oacc[i][j] = (facc){0.f, 0.f, 0.f, 0.f};
    float rp[4][4];
    #pragma unroll
    for (int i = 0; i < 4; ++i)
        #pragma unroll
        for (int r = 0; r < 4; ++r)
            rp[i][r] = 0.f;

    const int arow = lane >> 3;
    const int kc8s = ((lane & 7) ^ arow) * 8;    // swizzled K staging chunk
    const int vrow = lane >> 4;

    for (int kc = 0; kc < 4; ++kc) {
        __syncthreads();   // prior-iteration LDS reads complete
        #pragma unroll
        for (int t = 0; t < 4; ++t) {
            const int c = w * 4 + t;
            const int vc8s = ((lane & 15) ^ ((c * 4 + vrow) & 7)) * 8;
            gload16(Kg + (size_t)(kc*128 + c*8 + arow) * DH + kc8s, &Ks[c * 512]);
            gload16(VTg + (size_t)(c*4 + vrow) * SL + kc*128 + vc8s, &VTs[c * 512]);
        }
        __syncthreads();

        // ---- S = Q K^T (128x128) ----
        facc sacc[4][4];
        #pragma unroll
        for (int i = 0; i < 4; ++i)
            #pragma unroll
            for (int j = 0; j < 4; ++j)
                sacc[i][j] = (facc){0.f, 0.f, 0.f, 0.f};
        #pragma unroll
        for (int ks = 0; ks < 2; ++ks) {
            const int ch = (ks * 4 + qd) ^ (ln & 7);
            bfrag kf[4];
            #pragma unroll
            for (int j = 0; j < 4; ++j)
                kf[j] = *(const bfrag*)&Ks[(wns + j*16 + ln) * 64 + ch * 8];
            #pragma unroll
            for (int i = 0; i < 4; ++i)
                #pragma unroll
                for (int j = 0; j < 4; ++j)
                    sacc[i][j] = __builtin_amdgcn_mfma_f32_16x16x32_bf16(
                        qf[i][ks], kf[j], sacc[i][j], 0, 0, 0);
        }

        // ---- exp, row-sum (regs), E -> LDS (swizzled [q][key]) ----
        #pragma unroll
        for (int i = 0; i < 4; ++i) {
            #pragma unroll
            for (int r = 0; r < 4; ++r) {
                const int q = wm + i*16 + qd*4 + r;
                float p = 0.f;
                #pragma unroll
                for (int j = 0; j < 4; ++j) {
                    const float e = __expf(sacc[i][j][r] * 0.015625f);
                    const int key = wns + j*16 + ln;
                    const int c = (key >> 3) ^ (q & 7);
                    Es[q * 128 + c * 8 + (key & 7)] = f2bf(e);
                    p += e;
                }
                p += __shfl_xor(p, 1, 16);
                p += __shfl_xor(p, 2, 16);
                p += __shfl_xor(p, 4, 16);
                p += __shfl_xor(p, 8, 16);
                rp[i][r] += p;
            }
        }
        __syncthreads();

        // ---- O += E V (contract over 128 keys) ----
        #pragma unroll
        for (int ks2 = 0; ks2 < 4; ++ks2) {
            const int vch = (ks2 * 4 + qd) ^ (ln & 7);
            bfrag ea[4], vb[2];
            #pragma unroll
            for (int i = 0; i < 4; ++i) {
                const int q = wm + i*16 + ln;
                const int cs = (ks2*4 + qd) ^ (q & 7);
                ea[i] = *(const bfrag*)&Es[q * 128 + cs * 8];
            }
            #pragma unroll
            for (int j = 0; j < 2; ++j)
                vb[j] = *(const bfrag*)&VTs[(wnd + j*16 + ln) * 128 + vch * 8];
            #pragma unroll
            for (int i = 0; i < 4; ++i)
                #pragma unroll
                for (int j = 0; j < 2; ++j)
                    oacc[i][j] = __builtin_amdgcn_mfma_f32_16x16x32_bf16(
                        ea[i], vb[j], oacc[i][j], 0, 0, 0);
        }
    }

    // ---- combine row-sums across the two co-owning waves (reuse Ks) ----
    __syncthreads();
    float* rsls = (float*)Ks;
    if (ln == 0) {
        #pragma unroll
        for (int i = 0; i < 4; ++i)
            #pragma unroll
            for (int r = 0; r < 4; ++r)
                rsls[(w >> 1) * 128 + wm + i*16 + qd*4 + r] = rp[i][r];
    }
    __syncthreads();
    if (tid < 128) {
        const float t = rsls[tid] + rsls[128 + tid];
        RS[(size_t)(b * NH + h) * SL + qt * 128 + tid] = t;
        rsls[tid] = t;
    }
    __syncthreads();

    // ---- epilogue: normalize, store AO row-major [l][h*DH+d] bf16 ----
    #pragma unroll
    for (int i = 0; i < 4; ++i) {
        #pragma unroll
        for (int r = 0; r < 4; ++r) {
            const int q = wm + i*16 + qd*4 + r;
            const float inv = 1.f / rsls[q];
            const size_t rowo = ((size_t)(b*SL + qt*128 + q)) * DM + h*DH;
            #pragma unroll
            for (int j = 0; j < 2; ++j)
                AO[rowo + wnd + j*16 + ln] = f2bf(oacc[i][j][r] * inv);
        }
    }
}

// ---------------------------------------------------------------------------
// avg_attn via MFMA: one 64x64 avga tile per block (grid 8x8x8), 16-head
// loop. Q/K staged raw bf16 via global_load_lds; scores on the matrix pipe;
// exp + head-accumulate on VALU.
// ---------------------------------------------------------------------------
__global__ __launch_bounds__(256, 2)
void avg3_k(const ushort* __restrict__ Qm, const ushort* __restrict__ Km,
            const float* __restrict__ RS, float* __restrict__ avga)
{
    __shared__ ushort Qs[64 * 64];
    __shared__ ushort Kt[64 * 64];
    __shared__ float rss[64];
    const int tid  = threadIdx.x;
    const int w    = tid >> 6;
    const int lane = tid & 63;
    const int ln   = lane & 15, qd = lane >> 4;
    const int wq = (w & 1) * 32, wk = (w >> 1) * 32;
    const int kt = blockIdx.x, qt = blockIdx.y, b = blockIdx.z;

    const int arow = lane >> 3;
    const int kc8s = ((lane & 7) ^ arow) * 8;

    float acc[2][2][4];
    #pragma unroll
    for (int i = 0; i < 2; ++i)
        #pragma unroll
        for (int j = 0; j < 2; ++j)
            #pragma unroll
            for (int r = 0; r < 4; ++r)
                acc[i][j][r] = 0.f;

    for (int h = 0; h < NH; ++h) {
        const size_t ho = ((size_t)(b * NH + h)) * SL * DH;
        __syncthreads();   // prior head's frag reads complete
        #pragma unroll
        for (int t = 0; t < 2; ++t) {
            const int c = w * 2 + t;   // 8-row chunk
            gload16(Qm + ho + (size_t)(qt*64 + c*8 + arow) * DH + kc8s, &Qs[c * 512]);
            gload16(Km + ho + (size_t)(kt*64 + c*8 + arow) * DH + kc8s, &Kt[c * 512]);
        }
        if (tid < 64) rss[tid] = RS[(size_t)(b*NH + h)*SL + qt*64 + tid];
        __syncthreads();

        facc s[2][2];
        #pragma unroll
        for (int i = 0; i < 2; ++i)
            #pragma unroll
            for (int j = 0; j < 2; ++j)
                s[i][j] = (facc){0.f, 0.f, 0.f, 0.f};
        #pragma unroll
        for (int ks = 0; ks < 2; ++ks) {
            const int ch = (ks * 4 + qd) ^ (ln & 7);
            bfrag qa[2], kb[2];
            #pragma unroll
            for (int i = 0; i < 2; ++i)
                qa[i] = *(const bfrag*)&Qs[(wq + i*16 + ln) * 64 + ch * 8];
            #pragma unroll
            for (int j = 0; j < 2; ++j)
                kb[j] = *(const bfrag*)&Kt[(wk + j*16 + ln) * 64 + ch * 8];
            #pragma unroll
            for (int i = 0; i < 2; ++i)
                #pragma unroll
                for (int j = 0; j < 2; ++j)
                    s[i][j] = __builtin_amdgcn_mfma_f32_16x16x32_bf16(
                        qa[i], kb[j], s[i][j], 0, 0, 0);
        }
        // C/D layout: row(q) = qd*4+r, col(key) = ln
        #pragma unroll
        for (int i = 0; i < 2; ++i) {
            #pragma unroll
            for (int r = 0; r < 4; ++r) {
                const float ir = 0.0625f / rss[wq + i*16 + qd*4 + r];
                #pragma unroll
                for (int j = 0; j < 2; ++j)
                    acc[i][j][r] += __expf(s[i][j][r] * 0.015625f) * ir;
            }
        }
    }
    #pragma unroll
    for (int i = 0; i < 2; ++i) {
        #pragma unroll
        for (int r = 0; r < 4; ++r) {
            const int q = wq + i*16 + qd*4 + r;
            #pragma unroll
            for (int j = 0; j < 2; ++j)
                avga[((size_t)(b*SL + qt*64 + q)) * SL + kt*64 + wk + j*16 + ln]
                    = acc[i][j][r];
        }
    }
}

// ---------------------------------------------------------------------------
extern "C" void kernel_launch(void* const* d_in, const int* in_sizes, int n_in,
                              void* d_out, int out_size, void* d_ws, size_t ws_size,
                              hipStream_t stream)
{
    (void)in_sizes; (void)n_in; (void)out_size; (void)ws_size;
    const float* text  = (const float*)d_in[0];
    const float* image = (const float*)d_in[1];
    const float* Wq = (const float*)d_in[2];
    const float* bq = (const float*)d_in[3];
    const float* Wk = (const float*)d_in[4];
    const float* bk = (const float*)d_in[5];
    const float* Wv = (const float*)d_in[6];
    const float* bv = (const float*)d_in[7];
    const float* Wo = (const float*)d_in[8];
    const float* bo = (const float*)d_in[9];
    const float* W1 = (const float*)d_in[10];
    const float* b1 = (const float*)d_in[11];
    const float* W2 = (const float*)d_in[12];
    const float* b2 = (const float*)d_in[13];
    float* out = (float*)d_out;

    const size_t SZ   = (size_t)NB * SL * DM;   // 4,194,304
    const size_t HALF = SZ;                     // one direction of [16,NH,SL,DH]

    // ---- workspace layout (bf16 = ushort), ~82.1 MB ----
    ushort* xbf = (ushort*)d_ws;        // [8192,1024] text 0..4095, image 4096..
    ushort* Qb  = xbf + 2*SZ;           // [16,NH,SL,DH]
    ushort* Kb  = Qb  + 2*SZ;           // [16,NH,SL,DH]
    ushort* VT  = Kb  + 2*SZ;           // [16,NH,DH,SL]  (transposed V)
    ushort* AOt = VT  + 2*SZ;           // [4096,1024]
    ushort* Wt  = AOt + SZ;             // transposed-weight scratch
    float*  RS  = (float*)(Wt + 3*DM*DM);   // [8,NH,SL]
    ushort* AOi    = VT + HALF;         // reuses VT-image (dead after attn dir-1)
    ushort* hidden = Qb;                // reuses Q-text (dead after avg3)

    float* text_cross  = out;
    float* image_cross = out + SZ;
    float* comp        = out + 2*SZ;
    float* avga        = out + 3*SZ;

    const dim3 blk(256);
    const dim3 gQKV(8, 64);     // N=1024, M=8192
    const dim3 gHALFM(8, 32);   // N=1024, M=4096
    const dim3 ag(SL/128, NH, NB);

    // ---- convert activations to bf16 ----
    cvt_k<<<4096, blk, 0, stream>>>(text,  xbf);
    cvt_k<<<4096, blk, 0, stream>>>(image, xbf + SZ);

    // ---- Q/K/V projections (text+image batched along M) ----
    tconv_k<<<dim3(16,16), blk, 0, stream>>>(Wq, Wt,           DM, DM);
    tconv_k<<<dim3(16,16), blk, 0, stream>>>(Wk, Wt + DM*DM,   DM, DM);
    tconv_k<<<dim3(16,16), blk, 0, stream>>>(Wv, Wt + 2*DM*DM, DM, DM);
    mfma_gemm<1,1><<<gQKV, blk, 0, stream>>>(xbf, xbf, nullptr, DM, DM, DM, DM, DM,
                                             Wt,           DM, bq, nullptr, Qb);
    mfma_gemm<1,1><<<gQKV, blk, 0, stream>>>(xbf, xbf, nullptr, DM, DM, DM, DM, DM,
                                             Wt + DM*DM,   DM, bk, nullptr, Kb);
    mfma_gemm<0,3><<<gQKV, blk, 0, stream>>>(xbf, xbf, nullptr, DM, DM, DM, DM, DM,
                                             Wt + 2*DM*DM, DM, bv, nullptr, VT);

    // ---- attention dir-1 (Q text, K/V image), avg_attn, dir-2 ----
    attn2_k<<<ag, blk, 0, stream>>>(Qb, Kb + HALF, VT + HALF, AOt, RS);
    avg3_k<<<dim3(SL/64, SL/64, NB), blk, 0, stream>>>(Qb, Kb + HALF, RS, avga);
    attn2_k<<<ag, blk, 0, stream>>>(Qb + HALF, Kb, VT, AOi, RS);

    // ---- output projections ----
    tconv_k<<<dim3(16,16), blk, 0, stream>>>(Wo, Wt, DM, DM);
    mfma_gemm<0,0><<<gHALFM, blk, 0, stream>>>(AOt, AOt, nullptr, DM, DM, DM, DM, DM,
                                               Wt, DM, bo, text_cross, nullptr);
    mfma_gemm<0,0><<<gHALFM, blk, 0, stream>>>(AOi, AOi, nullptr, DM, DM, DM, DM, DM,
                                               Wt, DM, bo, image_cross, nullptr);

    // ---- MLP: concat(text, image, text_cross) @ W1 -> relu -> @ W2 ----
    tconv_k<<<dim3(16,48), blk, 0, stream>>>(W1, Wt, 3*DM, DM);
    mfma_gemm<2,2><<<gHALFM, blk, 0, stream>>>(xbf, xbf + SZ, text_cross,
                                               DM, 2*DM, 3*DM, DM, DM,
                                               Wt, 3*DM, b1, nullptr, hidden);
    tconv_k<<<dim3(16,16), blk, 0, stream>>>(W2, Wt, DM, DM);
    mfma_gemm<0,0><<<gHALFM, blk, 0, stream>>>(hidden, hidden, nullptr, DM, DM, DM, DM, DM,
                                               Wt, DM, b2, comp, nullptr);
}

// Round 7
// 401.140 us; speedup vs baseline: 6.6192x; 1.1303x over previous
//
#include <hip/hip_runtime.h>

#define NB 8
#define SL 512
#define DM 1024
#define NH 16
#define DH 64

using bfrag = __attribute__((ext_vector_type(8))) short;   // 8 bf16 (4 VGPRs)
using facc  = __attribute__((ext_vector_type(4))) float;   // 4 fp32 acc

__device__ __forceinline__ float bf2f(ushort u) {
    return __uint_as_float(((unsigned)u) << 16);
}
__device__ __forceinline__ ushort f2bf(float f) {
    unsigned x = __float_as_uint(f);
    return (ushort)((x + 0x7FFFu + ((x >> 16) & 1u)) >> 16);   // RNE
}
__device__ __forceinline__ float4 bf4_f4(ushort4 u) {
    return make_float4(bf2f(u.x), bf2f(u.y), bf2f(u.z), bf2f(u.w));
}
__device__ __forceinline__ unsigned pack2(float a, float b) {
    return (unsigned)f2bf(a) | ((unsigned)f2bf(b) << 16);
}
__device__ __forceinline__ void gload16(const ushort* g, ushort* l) {
    __builtin_amdgcn_global_load_lds(
        (const __attribute__((address_space(1))) unsigned*)g,
        (__attribute__((address_space(3))) unsigned*)l, 16, 0, 0);
}

// ---------------------------------------------------------------------------
// fp32 -> bf16 convert (4 elems/thread)
// ---------------------------------------------------------------------------
__global__ __launch_bounds__(256)
void cvt_k(const float* __restrict__ s, ushort* __restrict__ d) {
    const size_t i = (size_t)(blockIdx.x * 256 + threadIdx.x) * 4;
    const float4 f = *(const float4*)(s + i);
    *(ushort4*)(d + i) = make_ushort4(f2bf(f.x), f2bf(f.y), f2bf(f.z), f2bf(f.w));
}

// ---------------------------------------------------------------------------
// Transpose-convert: W[R,C] fp32 -> WT[C,R] bf16. grid (C/64, R/64).
// ---------------------------------------------------------------------------
__global__ __launch_bounds__(256)
void tconv_k(const float* __restrict__ W, ushort* __restrict__ WT,
             const int R, const int C) {
    __shared__ ushort T[64][68];
    const int tid = threadIdx.x;
    const int c0 = blockIdx.x * 64, r0 = blockIdx.y * 64;
    #pragma unroll
    for (int rr = 0; rr < 4; ++rr) {
        const int r = (tid >> 4) + rr * 16;
        const int c4 = (tid & 15) * 4;
        const float4 f = *(const float4*)(W + (size_t)(r0 + r) * C + c0 + c4);
        T[c4+0][r] = f2bf(f.x); T[c4+1][r] = f2bf(f.y);
        T[c4+2][r] = f2bf(f.z); T[c4+3][r] = f2bf(f.w);
    }
    __syncthreads();
    #pragma unroll
    for (int rr = 0; rr < 4; ++rr) {
        const int c = (tid >> 4) + rr * 16;
        const int r4 = (tid & 15) * 4;
        *(ushort4*)(WT + (size_t)(c0 + c) * R + r0 + r4) =
            make_ushort4(T[c][r4+0], T[c][r4+1], T[c][r4+2], T[c][r4+3]);
    }
}

// ---------------------------------------------------------------------------
// bf16 MFMA GEMM: 128x128 tile, 4 waves, BK=64, double-buffered LDS staging
// (one barrier per K-iter; stage(k+1) overlaps compute(k) -> hides the
// global_load_lds round-trip that made R5 latency-bound at 10.6k cyc/iter).
//   out[m,n] = ACT( sum_k A[m,k]*B[k,n] + bias[n] ),  B given as BT[n,k].
// A K-concat (A0|A1 bf16 | A2f fp32) and M-concat (rows >= Msplit from AM1,
// block-uniform). XCD swizzle: clustN=0 m-clustered (small B), 1 n-clustered
// (large B). XOR chunk swizzle on LDS -> conflict-free ds_read_b128.
// OMODE 0: fp32 row-major. 2: bf16 row-major. 4: fused QKV epilogue --
// segment n>>10 selects Q-scatter(sigmoid) / K-scatter(sigmoid) /
// V-transpose(none) with per-segment bias.
// ---------------------------------------------------------------------------
template<int ACT, int OMODE>
__global__ __launch_bounds__(256, 2)
void mfma_gemm(const ushort* __restrict__ A0, const ushort* __restrict__ A1,
               const float* __restrict__ A2f,
               const int KA1, const int KA2, const int Ktot,
               const int lda, const int ldaf,
               const ushort* __restrict__ AM1, const int Msplit,
               const ushort* __restrict__ BT, const int ldb,
               const float* __restrict__ bias, const float* __restrict__ biasK,
               const float* __restrict__ biasV,
               float* __restrict__ outf, ushort* __restrict__ outb,
               ushort* __restrict__ outbK, ushort* __restrict__ outbVT,
               const int clustN)
{
    __shared__ ushort sh[32768];   // 2 buffers x (As 8192 + Bs 8192), 64 KB
    const int tid  = threadIdx.x;
    const int w    = tid >> 6;
    const int lane = tid & 63;
    const int ln   = lane & 15, qd = lane >> 4;
    const int wm = (w & 1) * 64, wn = (w >> 1) * 64;

    // ---- XCD-clustered block swizzle ----
    const int NTg = gridDim.x, MTg = gridDim.y;
    const int L   = blockIdx.x + NTg * blockIdx.y;
    const int xcd = L & 7, sIdx = L >> 3;
    int mt, nt;
    if (clustN) { const int np = NTg >> 3; nt = xcd * np + sIdx % np; mt = sIdx / np; }
    else        { mt = xcd * (MTg >> 3) + sIdx / NTg; nt = sIdx - (sIdx / NTg) * NTg; }
    const int m0 = mt * 128, n0 = nt * 128;

    // ---- M-concat source select (block-uniform) ----
    const ushort* A0u = A0; const ushort* A1u = A1; int m0A = m0;
    if (Msplit && m0 >= Msplit) { A0u = AM1; A1u = AM1; m0A = m0 - Msplit; }

    const int arow = (lane >> 3);               // row-in-chunk 0..7
    const int kc8s = ((lane & 7) ^ arow) * 8;   // swizzled global k-chunk

    facc acc[4][4];
    #pragma unroll
    for (int i = 0; i < 4; ++i)
        #pragma unroll
        for (int j = 0; j < 4; ++j)
            acc[i][j] = (facc){0.f, 0.f, 0.f, 0.f};

    auto stage = [&](int k0, ushort* buf) {
        ushort* Asb = buf;
        ushort* Bsb = buf + 8192;
        #pragma unroll
        for (int t = 0; t < 4; ++t) {
            const int c = w * 4 + t;
            gload16(BT + (size_t)(n0 + c * 8 + arow) * ldb + k0 + kc8s,
                    &Bsb[c * 512]);
        }
        if (k0 < KA2) {
            const ushort* Ab; int ko;
            if (k0 < KA1) { Ab = A0u; ko = k0; }
            else          { Ab = A1u; ko = k0 - KA1; }
            #pragma unroll
            for (int t = 0; t < 4; ++t) {
                const int c = w * 4 + t;
                gload16(Ab + (size_t)(m0A + c * 8 + arow) * lda + ko + kc8s,
                        &Asb[c * 512]);
            }
        } else {           // fp32 source: load + convert + ds_write
            const int ko = k0 - KA2;
            #pragma unroll
            for (int t = 0; t < 4; ++t) {
                const int c = w * 4 + t;
                const float* src = A2f + (size_t)(m0A + c * 8 + arow) * ldaf + ko + kc8s;
                const float4 f0 = *(const float4*)src;
                const float4 f1 = *(const float4*)(src + 4);
                uint4 p;
                p.x = pack2(f0.x, f0.y); p.y = pack2(f0.z, f0.w);
                p.z = pack2(f1.x, f1.y); p.w = pack2(f1.z, f1.w);
                *(uint4*)&Asb[c * 512 + lane * 8] = p;
            }
        }
    };

    stage(0, sh);
    for (int k0 = 0; k0 < Ktot; k0 += 64) {
        ushort* cur = sh + ((k0 >> 6) & 1) * 16384;
        ushort* nxt = sh + (((k0 >> 6) & 1) ^ 1) * 16384;
        __syncthreads();                       // drains stage(k0) (vmcnt+lgkm)
        if (k0 + 64 < Ktot) stage(k0 + 64, nxt);   // overlaps compute below
        ushort* Asb = cur;
        ushort* Bsb = cur + 8192;
        #pragma unroll
        for (int ks = 0; ks < 2; ++ks) {
            const int ch = (ks * 4 + qd) ^ (ln & 7);   // swizzled chunk
            bfrag af[4], bfv[4];
            #pragma unroll
            for (int i = 0; i < 4; ++i)
                af[i] = *(const bfrag*)&Asb[(wm + i*16 + ln) * 64 + ch * 8];
            #pragma unroll
            for (int j = 0; j < 4; ++j)
                bfv[j] = *(const bfrag*)&Bsb[(wn + j*16 + ln) * 64 + ch * 8];
            #pragma unroll
            for (int i = 0; i < 4; ++i)
                #pragma unroll
                for (int j = 0; j < 4; ++j)
                    acc[i][j] = __builtin_amdgcn_mfma_f32_16x16x32_bf16(
                        af[i], bfv[j], acc[i][j], 0, 0, 0);
        }
    }

    if (OMODE == 4) {
        const int seg   = n0 >> 10;        // 0=Q 1=K 2=V (block-uniform)
        const int nloc0 = n0 & 1023;
        const float* bs = (seg == 0) ? bias : (seg == 1) ? biasK : biasV;
        if (seg < 2) {
            ushort* ob = (seg == 0) ? outb : outbK;
            #pragma unroll
            for (int j = 0; j < 4; ++j) {
                const int nl = nloc0 + wn + j * 16 + ln;
                const float bn = bs[nl];
                #pragma unroll
                for (int i = 0; i < 4; ++i) {
                    const int mb = m0 + wm + i * 16 + qd * 4;
                    #pragma unroll
                    for (int r = 0; r < 4; ++r) {
                        const float v = 1.f / (1.f + __expf(-(acc[i][j][r] + bn)));
                        const int m = mb + r;
                        const int g = m >> 9, l = m & 511;
                        ob[(((size_t)(g * NH + (nl >> 6))) * SL + l) * DH + (nl & 63)]
                            = f2bf(v);
                    }
                }
            }
        } else {
            // V: in-LDS swizzled transpose -> [g,h,d,l] coalesced stores
            __syncthreads();
            #pragma unroll
            for (int j = 0; j < 4; ++j) {
                const int n_l = wn + j * 16 + ln;
                const float bn = bs[nloc0 + n_l];
                #pragma unroll
                for (int i = 0; i < 4; ++i) {
                    #pragma unroll
                    for (int r = 0; r < 4; ++r) {
                        const int m_l = wm + i * 16 + qd * 4 + r;
                        const int c = (m_l >> 3) ^ (n_l & 7);
                        sh[n_l * 128 + c * 8 + (m_l & 7)] = f2bf(acc[i][j][r] + bn);
                    }
                }
            }
            __syncthreads();
            const int n_l = tid >> 1, half = tid & 1;
            const int nl = nloc0 + n_l;
            const int g = m0 >> 9, l0 = m0 & 511;
            ushort* dst = outbVT +
                (((size_t)(g * NH + (nl >> 6))) * DH + (nl & 63)) * SL + l0;
            #pragma unroll
            for (int u = 0; u < 8; ++u) {
                const int c = half * 8 + u;
                const int cs = c ^ (n_l & 7);
                *(uint4*)(dst + c * 8) = *(const uint4*)&sh[n_l * 128 + cs * 8];
            }
        }
        return;
    }

    // ---- standard epilogue: C/D layout col=lane&15, row=qd*4+r ----
    #pragma unroll
    for (int j = 0; j < 4; ++j) {
        const int n = n0 + wn + j * 16 + ln;
        const float bn = bias[n];
        #pragma unroll
        for (int i = 0; i < 4; ++i) {
            const int mb = m0 + wm + i * 16 + qd * 4;
            #pragma unroll
            for (int r = 0; r < 4; ++r) {
                float v = acc[i][j][r] + bn;
                if (ACT == 1)      v = 1.f / (1.f + __expf(-v));
                else if (ACT == 2) v = v > 0.f ? v : 0.f;
                const int m = mb + r;
                if (OMODE == 0) outf[(size_t)m * DM + n] = v;
                else            outb[(size_t)m * DM + n] = f2bf(v);
            }
        }
    }
}

// ---------------------------------------------------------------------------
// MFMA fuzzy attention. One (b,h,128-q-tile) per block, 4 waves (2x2).
// Q [g,h,l,d] / K [g,h,l,d] / VT [g,h,d,l], all bf16. Scores in [0,1] ->
// exp without max subtraction. E round-trips LDS (XOR-swizzled) to convert
// MFMA C-layout -> A-layout for PV. XOR chunk swizzle on K/VT staging.
// LDS = 16K (K) + 16K (VT) + 32K (E) = 64 KB -> 2 blocks/CU.
// ---------------------------------------------------------------------------
__global__ __launch_bounds__(256, 2)
void attn2_k(const ushort* __restrict__ Qm, const ushort* __restrict__ Km,
             const ushort* __restrict__ VTm, ushort* __restrict__ AO,
             float* __restrict__ RS)
{
    __shared__ ushort Ks[128 * 64];
    __shared__ ushort VTs[64 * 128];
    __shared__ ushort Es[128 * 128];
    const int tid  = threadIdx.x;
    const int w    = tid >> 6;
    const int lane = tid & 63;
    const int ln   = lane & 15, qd = lane >> 4;
    const int wm  = (w & 1) * 64;          // q offset of this wave
    const int wns = (w >> 1) * 64;         // key offset (S stage)
    const int wnd = (w >> 1) * 32;         // d offset (PV stage)
    const int qt = blockIdx.x, h = blockIdx.y, b = blockIdx.z;
    const size_t ho = ((size_t)(b * NH + h)) * SL * DH;
    const ushort* Qg  = Qm  + ho + (size_t)qt * 128 * DH;
    const ushort* Kg  = Km  + ho;
    const ushort* VTg = VTm + ho;

    bfrag qf[4][2];
    #pragma unroll
    for (int i = 0; i < 4; ++i)
        #pragma unroll
        for (int ks = 0; ks < 2; ++ks)
            qf[i][ks] = *(const bfrag*)(Qg + (size_t)(wm + i*16 + ln) * DH + ks*32 + qd*8);

    facc oacc[4][2];
    #pragma unroll
    for (int i = 0; i < 4; ++i)
        #pragma unroll
        for (int j = 0; j < 2; ++j)
            oacc[i][j] = (facc){0.f, 0.f, 0.f, 0.f};
    float rp[4][4];
    #pragma unroll
    for (int i = 0; i < 4; ++i)
        #pragma unroll
        for (int r = 0; r < 4; ++r)
            rp[i][r] = 0.f;

    const int arow = lane >> 3;
    const int kc8s = ((lane & 7) ^ arow) * 8;
    const int vrow = lane >> 4;

    for (int kc = 0; kc < 4; ++kc) {
        __syncthreads();
        #pragma unroll
        for (int t = 0; t < 4; ++t) {
            const int c = w * 4 + t;
            const int vc8s = ((lane & 15) ^ ((c * 4 + vrow) & 7)) * 8;
            gload16(Kg + (size_t)(kc*128 + c*8 + arow) * DH + kc8s, &Ks[c * 512]);
            gload16(VTg + (size_t)(c*4 + vrow) * SL + kc*128 + vc8s, &VTs[c * 512]);
        }
        __syncthreads();

        facc sacc[4][4];
        #pragma unroll
        for (int i = 0; i < 4; ++i)
            #pragma unroll
            for (int j = 0; j < 4; ++j)
                sacc[i][j] = (facc){0.f, 0.f, 0.f, 0.f};
        #pragma unroll
        for (int ks = 0; ks < 2; ++ks) {
            const int ch = (ks * 4 + qd) ^ (ln & 7);
            bfrag kf[4];
            #pragma unroll
            for (int j = 0; j < 4; ++j)
                kf[j] = *(const bfrag*)&Ks[(wns + j*16 + ln) * 64 + ch * 8];
            #pragma unroll
            for (int i = 0; i < 4; ++i)
                #pragma unroll
                for (int j = 0; j < 4; ++j)
                    sacc[i][j] = __builtin_amdgcn_mfma_f32_16x16x32_bf16(
                        qf[i][ks], kf[j], sacc[i][j], 0, 0, 0);
        }

        #pragma unroll
        for (int i = 0; i < 4; ++i) {
            #pragma unroll
            for (int r = 0; r < 4; ++r) {
                const int q = wm + i*16 + qd*4 + r;
                float p = 0.f;
                #pragma unroll
                for (int j = 0; j < 4; ++j) {
                    const float e = __expf(sacc[i][j][r] * 0.015625f);
                    const int key = wns + j*16 + ln;
                    const int c = (key >> 3) ^ (q & 7);
                    Es[q * 128 + c * 8 + (key & 7)] = f2bf(e);
                    p += e;
                }
                p += __shfl_xor(p, 1, 16);
                p += __shfl_xor(p, 2, 16);
                p += __shfl_xor(p, 4, 16);
                p += __shfl_xor(p, 8, 16);
                rp[i][r] += p;
            }
        }
        __syncthreads();

        #pragma unroll
        for (int ks2 = 0; ks2 < 4; ++ks2) {
            const int vch = (ks2 * 4 + qd) ^ (ln & 7);
            bfrag ea[4], vb[2];
            #pragma unroll
            for (int i = 0; i < 4; ++i) {
                const int q = wm + i*16 + ln;
                const int cs = (ks2*4 + qd) ^ (q & 7);
                ea[i] = *(const bfrag*)&Es[q * 128 + cs * 8];
            }
            #pragma unroll
            for (int j = 0; j < 2; ++j)
                vb[j] = *(const bfrag*)&VTs[(wnd + j*16 + ln) * 128 + vch * 8];
            #pragma unroll
            for (int i = 0; i < 4; ++i)
                #pragma unroll
                for (int j = 0; j < 2; ++j)
                    oacc[i][j] = __builtin_amdgcn_mfma_f32_16x16x32_bf16(
                        ea[i], vb[j], oacc[i][j], 0, 0, 0);
        }
    }

    __syncthreads();
    float* rsls = (float*)Ks;
    if (ln == 0) {
        #pragma unroll
        for (int i = 0; i < 4; ++i)
            #pragma unroll
            for (int r = 0; r < 4; ++r)
                rsls[(w >> 1) * 128 + wm + i*16 + qd*4 + r] = rp[i][r];
    }
    __syncthreads();
    if (tid < 128) {
        const float t = rsls[tid] + rsls[128 + tid];
        RS[(size_t)(b * NH + h) * SL + qt * 128 + tid] = t;
        rsls[tid] = t;
    }
    __syncthreads();

    #pragma unroll
    for (int i = 0; i < 4; ++i) {
        #pragma unroll
        for (int r = 0; r < 4; ++r) {
            const int q = wm + i*16 + qd*4 + r;
            const float inv = 1.f / rsls[q];
            const size_t rowo = ((size_t)(b*SL + qt*128 + q)) * DM + h*DH;
            #pragma unroll
            for (int j = 0; j < 2; ++j)
                AO[rowo + wnd + j*16 + ln] = f2bf(oacc[i][j][r] * inv);
        }
    }
}

// ---------------------------------------------------------------------------
// avg_attn via MFMA: one 64x64 avga tile per block (grid 8x8x8), 16-head
// loop. Q/K staged raw bf16 via global_load_lds; scores on the matrix pipe;
// exp + head-accumulate on VALU.
// ---------------------------------------------------------------------------
__global__ __launch_bounds__(256, 2)
void avg3_k(const ushort* __restrict__ Qm, const ushort* __restrict__ Km,
            const float* __restrict__ RS, float* __restrict__ avga)
{
    __shared__ ushort Qs[64 * 64];
    __shared__ ushort Kt[64 * 64];
    __shared__ float rss[64];
    const int tid  = threadIdx.x;
    const int w    = tid >> 6;
    const int lane = tid & 63;
    const int ln   = lane & 15, qd = lane >> 4;
    const int wq = (w & 1) * 32, wk = (w >> 1) * 32;
    const int kt = blockIdx.x, qt = blockIdx.y, b = blockIdx.z;

    const int arow = lane >> 3;
    const int kc8s = ((lane & 7) ^ arow) * 8;

    float acc[2][2][4];
    #pragma unroll
    for (int i = 0; i < 2; ++i)
        #pragma unroll
        for (int j = 0; j < 2; ++j)
            #pragma unroll
            for (int r = 0; r < 4; ++r)
                acc[i][j][r] = 0.f;

    for (int h = 0; h < NH; ++h) {
        const size_t ho = ((size_t)(b * NH + h)) * SL * DH;
        __syncthreads();
        #pragma unroll
        for (int t = 0; t < 2; ++t) {
            const int c = w * 2 + t;
            gload16(Qm + ho + (size_t)(qt*64 + c*8 + arow) * DH + kc8s, &Qs[c * 512]);
            gload16(Km + ho + (size_t)(kt*64 + c*8 + arow) * DH + kc8s, &Kt[c * 512]);
        }
        if (tid < 64) rss[tid] = RS[(size_t)(b*NH + h)*SL + qt*64 + tid];
        __syncthreads();

        facc s[2][2];
        #pragma unroll
        for (int i = 0; i < 2; ++i)
            #pragma unroll
            for (int j = 0; j < 2; ++j)
                s[i][j] = (facc){0.f, 0.f, 0.f, 0.f};
        #pragma unroll
        for (int ks = 0; ks < 2; ++ks) {
            const int ch = (ks * 4 + qd) ^ (ln & 7);
            bfrag qa[2], kb[2];
            #pragma unroll
            for (int i = 0; i < 2; ++i)
                qa[i] = *(const bfrag*)&Qs[(wq + i*16 + ln) * 64 + ch * 8];
            #pragma unroll
            for (int j = 0; j < 2; ++j)
                kb[j] = *(const bfrag*)&Kt[(wk + j*16 + ln) * 64 + ch * 8];
            #pragma unroll
            for (int i = 0; i < 2; ++i)
                #pragma unroll
                for (int j = 0; j < 2; ++j)
                    s[i][j] = __builtin_amdgcn_mfma_f32_16x16x32_bf16(
                        qa[i], kb[j], s[i][j], 0, 0, 0);
        }
        #pragma unroll
        for (int i = 0; i < 2; ++i) {
            #pragma unroll
            for (int r = 0; r < 4; ++r) {
                const float ir = 0.0625f / rss[wq + i*16 + qd*4 + r];
                #pragma unroll
                for (int j = 0; j < 2; ++j)
                    acc[i][j][r] += __expf(s[i][j][r] * 0.015625f) * ir;
            }
        }
    }
    #pragma unroll
    for (int i = 0; i < 2; ++i) {
        #pragma unroll
        for (int r = 0; r < 4; ++r) {
            const int q = wq + i*16 + qd*4 + r;
            #pragma unroll
            for (int j = 0; j < 2; ++j)
                avga[((size_t)(b*SL + qt*64 + q)) * SL + kt*64 + wk + j*16 + ln]
                    = acc[i][j][r];
        }
    }
}

// ---------------------------------------------------------------------------
extern "C" void kernel_launch(void* const* d_in, const int* in_sizes, int n_in,
                              void* d_out, int out_size, void* d_ws, size_t ws_size,
                              hipStream_t stream)
{
    (void)in_sizes; (void)n_in; (void)out_size; (void)ws_size;
    const float* text  = (const float*)d_in[0];
    const float* image = (const float*)d_in[1];
    const float* Wq = (const float*)d_in[2];
    const float* bq = (const float*)d_in[3];
    const float* Wk = (const float*)d_in[4];
    const float* bk = (const float*)d_in[5];
    const float* Wv = (const float*)d_in[6];
    const float* bv = (const float*)d_in[7];
    const float* Wo = (const float*)d_in[8];
    const float* bo = (const float*)d_in[9];
    const float* W1 = (const float*)d_in[10];
    const float* b1 = (const float*)d_in[11];
    const float* W2 = (const float*)d_in[12];
    const float* b2 = (const float*)d_in[13];
    float* out = (float*)d_out;

    const size_t SZ   = (size_t)NB * SL * DM;   // 4,194,304
    const size_t HALF = SZ;

    // ---- workspace layout (bf16 = ushort), ~82.1 MB ----
    ushort* xbf = (ushort*)d_ws;        // [8192,1024] text 0..4095, image 4096..
    ushort* Qb  = xbf + 2*SZ;           // [16,NH,SL,DH]
    ushort* Kb  = Qb  + 2*SZ;           // [16,NH,SL,DH]
    ushort* VT  = Kb  + 2*SZ;           // [16,NH,DH,SL]
    ushort* AOt = VT  + 2*SZ;           // [4096,1024]
    ushort* Wt  = AOt + SZ;             // transposed-weight scratch [3072,1024]
    float*  RS  = (float*)(Wt + 3*DM*DM);   // [8,NH,SL]
    ushort* AOi    = VT + HALF;         // reuses VT-image (dead after attn dir-1)
    ushort* hidden = Qb;                // reuses Q-text (dead after avg3)

    float* text_cross = out;            // fused out-proj writes rows 0..8191
    float* comp       = out + 2*SZ;
    float* avga       = out + 3*SZ;

    const dim3 blk(256);

    // ---- convert activations to bf16 ----
    cvt_k<<<4096, blk, 0, stream>>>(text,  xbf);
    cvt_k<<<4096, blk, 0, stream>>>(image, xbf + SZ);

    // ---- fused Q/K/V projection: M=8192, N=3072 (Wt = Wq^T|Wk^T|Wv^T) ----
    tconv_k<<<dim3(16,16), blk, 0, stream>>>(Wq, Wt,           DM, DM);
    tconv_k<<<dim3(16,16), blk, 0, stream>>>(Wk, Wt + DM*DM,   DM, DM);
    tconv_k<<<dim3(16,16), blk, 0, stream>>>(Wv, Wt + 2*DM*DM, DM, DM);
    mfma_gemm<0,4><<<dim3(24,64), blk, 0, stream>>>(
        xbf, xbf, nullptr, DM, DM, DM, DM, DM, nullptr, 0,
        Wt, DM, bq, bk, bv, nullptr, Qb, Kb, VT, 1);

    // ---- attention dir-1 (Q text, K/V image), avg_attn, dir-2 ----
    attn2_k<<<dim3(SL/128, NH, NB), blk, 0, stream>>>(Qb, Kb + HALF, VT + HALF, AOt, RS);
    avg3_k<<<dim3(SL/64, SL/64, NB), blk, 0, stream>>>(Qb, Kb + HALF, RS, avga);
    attn2_k<<<dim3(SL/128, NH, NB), blk, 0, stream>>>(Qb + HALF, Kb, VT, AOi, RS);

    // ---- fused output projections: M=8192 (AOt rows 0.., AOi rows 4096..) ----
    tconv_k<<<dim3(16,16), blk, 0, stream>>>(Wo, Wt, DM, DM);
    mfma_gemm<0,0><<<dim3(8,64), blk, 0, stream>>>(
        AOt, AOt, nullptr, DM, DM, DM, DM, DM, AOi, 4096,
        Wt, DM, bo, nullptr, nullptr, text_cross, nullptr, nullptr, nullptr, 0);

    // ---- MLP: concat(text, image, text_cross) @ W1 -> relu -> @ W2 ----
    tconv_k<<<dim3(16,48), blk, 0, stream>>>(W1, Wt, 3*DM, DM);
    mfma_gemm<2,2><<<dim3(8,32), blk, 0, stream>>>(
        xbf, xbf + SZ, text_cross, DM, 2*DM, 3*DM, DM, DM, nullptr, 0,
        Wt, 3*DM, b1, nullptr, nullptr, nullptr, hidden, nullptr, nullptr, 0);
    tconv_k<<<dim3(16,16), blk, 0, stream>>>(W2, Wt, DM, DM);
    mfma_gemm<0,0><<<dim3(8,32), blk, 0, stream>>>(
        hidden, hidden, nullptr, DM, DM, DM, DM, DM, nullptr, 0,
        Wt, DM, b2, nullptr, nullptr, comp, nullptr, nullptr, nullptr, 0);
}